// Round 15
// baseline (240.339 us; speedup 1.0000x reference)
//
#include <hip/hip_runtime.h>
#include <hip/hip_bf16.h>
#include <cstdint>

typedef __hip_bfloat16 bf16;
typedef unsigned short u16;
typedef __attribute__((ext_vector_type(8))) short bf16x8;
typedef __attribute__((ext_vector_type(4))) float f32x4;

static __device__ __forceinline__ float bs2f(u16 s) {
  unsigned int u = ((unsigned int)s) << 16;
  float f;
  __builtin_memcpy(&f, &u, 4);
  return f;
}
static __device__ __forceinline__ u16 f2bs(float f) {
  bf16 h = __float2bfloat16(f);
  u16 s;
  __builtin_memcpy(&s, &h, 2);
  return s;
}
static __device__ __forceinline__ float ldf(const void* p, size_t i, int f32) {
  return f32 ? ((const float*)p)[i] : bs2f(((const u16*)p)[i]);
}

// ---------------------------------------------------------------------------
// dtype detection on a 256 KB sample of x.
// ---------------------------------------------------------------------------
__global__ __launch_bounds__(256) void detect_dtype(const uint4* __restrict__ xs,
                                                    int* __restrict__ flag) {
  int i = blockIdx.x * 256 + threadIdx.x;
  uint4 v = xs[i];
  bool hit = false;
#pragma unroll
  for (int j = 0; j < 4; ++j) {
    unsigned w = (j == 0) ? v.x : (j == 1) ? v.y : (j == 2) ? v.z : v.w;
    if ((w & 0x7F80u) == 0x7F80u) hit = true;
    if ((w & 0x7F800000u) == 0x7F800000u) hit = true;
  }
  unsigned long long mask = __ballot(hit);
  if (mask != 0ull && (threadIdx.x & 63) == 0) atomicOr(flag, 1);
}

// one-time gate weights conversion -> bf16 gwb[64][128], f32 gbf[64]
__global__ __launch_bounds__(256) void prep_gate(
    const void* __restrict__ gate_w, const void* __restrict__ gate_b,
    u16* __restrict__ gwb, float* __restrict__ gbf,
    const int* __restrict__ dtf) {
  const int f32 = *dtf;
  int t = threadIdx.x;
  for (int i = t; i < 8192; i += 256)
    gwb[i] = f32 ? f2bs(((const float*)gate_w)[i]) : ((const u16*)gate_w)[i];
  if (t < 64) gbf[t] = ldf(gate_b, t, f32);
}

// ---------------------------------------------------------------------------
// transpose [b][c=512][N] -> [b][N][512] bf16; optional fused heat partials.
// ---------------------------------------------------------------------------
__global__ __launch_bounds__(256) void transpose_bf16(
    const void* __restrict__ src, u16* __restrict__ dst, int N,
    float* __restrict__ heat, const int* __restrict__ dtf) {
  const int f32 = *dtf;
  const int b = blockIdx.z, n0 = blockIdx.x * 64, c0 = blockIdx.y * 64;
  const int t = threadIdx.x;
  __shared__ __align__(16) u16 tile[64][72];
#pragma unroll
  for (int j = 0; j < 2; ++j) {
    int cc = (t >> 3) + j * 32;
    int nn = (t & 7) * 8;
    u16 tmp[8];
    if (f32) {
      const float* s4 = (const float*)src + ((size_t)(b * 512 + c0 + cc)) * N + n0 + nn;
#pragma unroll
      for (int u = 0; u < 8; ++u) tmp[u] = f2bs(s4[u]);
    } else {
      *reinterpret_cast<uint4*>(tmp) = *reinterpret_cast<const uint4*>(
          (const u16*)src + ((size_t)(b * 512 + c0 + cc)) * N + n0 + nn);
    }
    *reinterpret_cast<uint4*>(&tile[cc][nn]) = *reinterpret_cast<const uint4*>(tmp);
  }
  __syncthreads();
  if (heat != nullptr && t < 32) {
    float s = 0.f;
#pragma unroll 8
    for (int cc = 0; cc < 64; ++cc)
      s += bs2f(tile[cc][2 * t]) + bs2f(tile[cc][2 * t + 1]);
    int y = blockIdx.x;
    atomicAdd(&heat[b * 1024 + (y >> 1) * 32 + t], s);
  }
#pragma unroll
  for (int j = 0; j < 2; ++j) {
    int nn = (t >> 3) + j * 32;
    int cc0 = (t & 7) * 8;
    u16 tmp[8];
#pragma unroll
    for (int u = 0; u < 8; ++u) tmp[u] = tile[cc0 + u][nn];
    *reinterpret_cast<uint4*>(&dst[((size_t)b * N + n0 + nn) * 512 + c0 + cc0]) =
        *reinterpret_cast<const uint4*>(tmp);
  }
}

// ---------------------------------------------------------------------------
// 128m x 128o MFMA conv1x1 GEMM (round 15: 2 o-tiles per block on the
// r13-proven named-scalar dbuf. MFMA/barrier 16 -> 32; A re-staging halves;
// grid (32,4,2) = 256 blocks = 1/CU exactly (latency covered by the dbuf
// pipeline, as validated on gather at 1/CU). LDS 73.7 KB. acc[2][8].
// MODE 0 (q): outputs scaled by 0.125 (exact shift); h now varies per ot.
// ---------------------------------------------------------------------------
template<int MODE>
__global__ __launch_bounds__(256) void gemm128(
    const u16* __restrict__ A, const void* __restrict__ W,
    const void* __restrict__ bias, u16* __restrict__ o0,
    void* __restrict__ ob, float* __restrict__ qsum, int M,
    const int* __restrict__ dtf) {
  const int f32 = *dtf;
  const int b = blockIdx.z, m0 = blockIdx.x * 128, oo0 = blockIdx.y * 128;
  const int t = threadIdx.x, w = t >> 6, lane = t & 63;
  const int quad = lane >> 4, c = lane & 15;
  __shared__ __align__(16) u16 As[2][128][72];
  __shared__ __align__(16) u16 Ws[2][128][72];
  f32x4 acc[2][8];
#pragma unroll
  for (int nt = 0; nt < 2; ++nt)
#pragma unroll
    for (int ot = 0; ot < 8; ++ot) acc[nt][ot] = (f32x4){0.f, 0.f, 0.f, 0.f};
  const u16* Ab = A + (size_t)b * M * 512;
  const int arow = t >> 1, acol = (t & 1) * 32;
  const int wrow = t >> 2, wcol = (t & 3) * 16;

  uint4 ar0, ar1, ar2, ar3, wr0, wr1, wr2, wr3, wr4, wr5, wr6, wr7;

  {
    const uint4* gs = reinterpret_cast<const uint4*>(Ab + (size_t)(m0 + arow) * 512 + acol);
    uint4* ad = reinterpret_cast<uint4*>(&As[0][arow][acol]);
    ad[0] = gs[0]; ad[1] = gs[1]; ad[2] = gs[2]; ad[3] = gs[3];
    if (f32) {
      const float* gw0 = (const float*)W + (size_t)(oo0 + wrow) * 512 + wcol;
#pragma unroll
      for (int e = 0; e < 16; ++e) Ws[0][wrow][wcol + e] = f2bs(gw0[e]);
      const float* gw1 = (const float*)W + (size_t)(oo0 + 64 + wrow) * 512 + wcol;
#pragma unroll
      for (int e = 0; e < 16; ++e) Ws[0][64 + wrow][wcol + e] = f2bs(gw1[e]);
    } else {
      const u16* gw0 = (const u16*)W + (size_t)(oo0 + wrow) * 512 + wcol;
      *reinterpret_cast<uint4*>(&Ws[0][wrow][wcol])     = *reinterpret_cast<const uint4*>(gw0);
      *reinterpret_cast<uint4*>(&Ws[0][wrow][wcol + 8]) = *reinterpret_cast<const uint4*>(gw0 + 8);
      const u16* gw1 = (const u16*)W + (size_t)(oo0 + 64 + wrow) * 512 + wcol;
      *reinterpret_cast<uint4*>(&Ws[0][64 + wrow][wcol])     = *reinterpret_cast<const uint4*>(gw1);
      *reinterpret_cast<uint4*>(&Ws[0][64 + wrow][wcol + 8]) = *reinterpret_cast<const uint4*>(gw1 + 8);
    }
    const uint4* gs1 = reinterpret_cast<const uint4*>(Ab + (size_t)(m0 + arow) * 512 + 64 + acol);
    ar0 = gs1[0]; ar1 = gs1[1]; ar2 = gs1[2]; ar3 = gs1[3];
    if (f32) {
      const uint4* gw0 = reinterpret_cast<const uint4*>(
          (const float*)W + (size_t)(oo0 + wrow) * 512 + 64 + wcol);
      wr0 = gw0[0]; wr1 = gw0[1]; wr2 = gw0[2]; wr3 = gw0[3];
      const uint4* gw1 = reinterpret_cast<const uint4*>(
          (const float*)W + (size_t)(oo0 + 64 + wrow) * 512 + 64 + wcol);
      wr4 = gw1[0]; wr5 = gw1[1]; wr6 = gw1[2]; wr7 = gw1[3];
    } else {
      const uint4* gw0 = reinterpret_cast<const uint4*>(
          (const u16*)W + (size_t)(oo0 + wrow) * 512 + 64 + wcol);
      wr0 = gw0[0]; wr1 = gw0[1];
      const uint4* gw1 = reinterpret_cast<const uint4*>(
          (const u16*)W + (size_t)(oo0 + 64 + wrow) * 512 + 64 + wcol);
      wr2 = gw1[0]; wr3 = gw1[1];
    }
  }

  for (int ki = 0; ki < 8; ++ki) {
    __syncthreads();
    const int bf = ki & 1;

    // ks = 0 half
    {
      bf16x8 av0 = *reinterpret_cast<const bf16x8*>(&As[bf][w * 32 + c][quad * 8]);
      bf16x8 av1 = *reinterpret_cast<const bf16x8*>(&As[bf][w * 32 + 16 + c][quad * 8]);
#pragma unroll
      for (int ot = 0; ot < 8; ++ot) {
        bf16x8 wv = *reinterpret_cast<const bf16x8*>(&Ws[bf][ot * 16 + c][quad * 8]);
        if (MODE == 3) {
          acc[0][ot] = __builtin_amdgcn_mfma_f32_16x16x32_bf16(wv, av0, acc[0][ot], 0, 0, 0);
          acc[1][ot] = __builtin_amdgcn_mfma_f32_16x16x32_bf16(wv, av1, acc[1][ot], 0, 0, 0);
        } else {
          acc[0][ot] = __builtin_amdgcn_mfma_f32_16x16x32_bf16(av0, wv, acc[0][ot], 0, 0, 0);
          acc[1][ot] = __builtin_amdgcn_mfma_f32_16x16x32_bf16(av1, wv, acc[1][ot], 0, 0, 0);
        }
      }
    }

    if (ki + 1 < 8) {
      uint4* ad = reinterpret_cast<uint4*>(&As[bf ^ 1][arow][acol]);
      ad[0] = ar0; ad[1] = ar1; ad[2] = ar2; ad[3] = ar3;
      if (f32) {
        float tf[16];
        __builtin_memcpy(&tf[0],  &wr0, 16);
        __builtin_memcpy(&tf[4],  &wr1, 16);
        __builtin_memcpy(&tf[8],  &wr2, 16);
        __builtin_memcpy(&tf[12], &wr3, 16);
#pragma unroll
        for (int e = 0; e < 16; ++e) Ws[bf ^ 1][wrow][wcol + e] = f2bs(tf[e]);
        float tg[16];
        __builtin_memcpy(&tg[0],  &wr4, 16);
        __builtin_memcpy(&tg[4],  &wr5, 16);
        __builtin_memcpy(&tg[8],  &wr6, 16);
        __builtin_memcpy(&tg[12], &wr7, 16);
#pragma unroll
        for (int e = 0; e < 16; ++e) Ws[bf ^ 1][64 + wrow][wcol + e] = f2bs(tg[e]);
      } else {
        *reinterpret_cast<uint4*>(&Ws[bf ^ 1][wrow][wcol])          = wr0;
        *reinterpret_cast<uint4*>(&Ws[bf ^ 1][wrow][wcol + 8])      = wr1;
        *reinterpret_cast<uint4*>(&Ws[bf ^ 1][64 + wrow][wcol])     = wr2;
        *reinterpret_cast<uint4*>(&Ws[bf ^ 1][64 + wrow][wcol + 8]) = wr3;
      }
      if (ki + 2 < 8) {
        const int k0 = (ki + 2) * 64;
        const uint4* gs = reinterpret_cast<const uint4*>(Ab + (size_t)(m0 + arow) * 512 + k0 + acol);
        ar0 = gs[0]; ar1 = gs[1]; ar2 = gs[2]; ar3 = gs[3];
        if (f32) {
          const uint4* gw0 = reinterpret_cast<const uint4*>(
              (const float*)W + (size_t)(oo0 + wrow) * 512 + k0 + wcol);
          wr0 = gw0[0]; wr1 = gw0[1]; wr2 = gw0[2]; wr3 = gw0[3];
          const uint4* gw1 = reinterpret_cast<const uint4*>(
              (const float*)W + (size_t)(oo0 + 64 + wrow) * 512 + k0 + wcol);
          wr4 = gw1[0]; wr5 = gw1[1]; wr6 = gw1[2]; wr7 = gw1[3];
        } else {
          const uint4* gw0 = reinterpret_cast<const uint4*>(
              (const u16*)W + (size_t)(oo0 + wrow) * 512 + k0 + wcol);
          wr0 = gw0[0]; wr1 = gw0[1];
          const uint4* gw1 = reinterpret_cast<const uint4*>(
              (const u16*)W + (size_t)(oo0 + 64 + wrow) * 512 + k0 + wcol);
          wr2 = gw1[0]; wr3 = gw1[1];
        }
      }
    }

    // ks = 1 half
    {
      bf16x8 av0 = *reinterpret_cast<const bf16x8*>(&As[bf][w * 32 + c][32 + quad * 8]);
      bf16x8 av1 = *reinterpret_cast<const bf16x8*>(&As[bf][w * 32 + 16 + c][32 + quad * 8]);
#pragma unroll
      for (int ot = 0; ot < 8; ++ot) {
        bf16x8 wv = *reinterpret_cast<const bf16x8*>(&Ws[bf][ot * 16 + c][32 + quad * 8]);
        if (MODE == 3) {
          acc[0][ot] = __builtin_amdgcn_mfma_f32_16x16x32_bf16(wv, av0, acc[0][ot], 0, 0, 0);
          acc[1][ot] = __builtin_amdgcn_mfma_f32_16x16x32_bf16(wv, av1, acc[1][ot], 0, 0, 0);
        } else {
          acc[0][ot] = __builtin_amdgcn_mfma_f32_16x16x32_bf16(av0, wv, acc[0][ot], 0, 0, 0);
          acc[1][ot] = __builtin_amdgcn_mfma_f32_16x16x32_bf16(av1, wv, acc[1][ot], 0, 0, 0);
        }
      }
    }
  }

  if (MODE == 0) {
#pragma unroll
    for (int ot = 0; ot < 8; ++ot) {
      int o = oo0 + ot * 16 + c;
      int hh = o >> 6, d = o & 63;
      int bh = b * 8 + hh;
      float bv = ldf(bias, o, f32);
      float qs = 0.f;
#pragma unroll
      for (int nt = 0; nt < 2; ++nt)
#pragma unroll
        for (int r = 0; r < 4; ++r) {
          int m = m0 + w * 32 + nt * 16 + quad * 4 + r;
          float qv = acc[nt][ot][r] + bv;
          o0[((size_t)bh * M + m) * 64 + d] = f2bs(qv * 0.125f);
          qs += qv;
        }
      qs += __shfl_xor(qs, 16, 64);
      qs += __shfl_xor(qs, 32, 64);
      if (quad == 0) atomicAdd(&qsum[bh * 64 + d], qs);
    }
  } else {
#pragma unroll
    for (int ot = 0; ot < 8; ++ot)
#pragma unroll
      for (int r = 0; r < 4; ++r) {
        int o = oo0 + ot * 16 + quad * 4 + r;
        float bv = ldf(bias, o, f32);
#pragma unroll
        for (int nt = 0; nt < 2; ++nt) {
          int m = m0 + w * 32 + nt * 16 + c;
          float val = acc[nt][ot][r] + bv;
          size_t oi_ = ((size_t)(b * 512 + o)) * M + m;
          if (f32) ((float*)ob)[oi_] = val;
          else     ((u16*)ob)[oi_] = f2bs(val);
        }
      }
  }
}

// ---------------------------------------------------------------------------
// 64x64 MFMA conv1x1 GEMM for kv_up (r13-proven dbuf + named-scalar prefetch,
// 1 barrier/K-step). kb [bh][m][64], v2 swizzled.
// v2 index for V[d][m] (per bh): ((ch*2+s)*4+dt)*512 + (q2*16+cc)*8 + e
// ---------------------------------------------------------------------------
__global__ __launch_bounds__(256) void gemm_kv(
    const u16* __restrict__ A, const void* __restrict__ W,
    const void* __restrict__ bias, u16* __restrict__ kb, u16* __restrict__ v2,
    int M, const int* __restrict__ dtf) {
  const int f32 = *dtf;
  const int b = blockIdx.z, m0 = blockIdx.x * 64, oo0 = blockIdx.y * 64;
  const int t = threadIdx.x, w = t >> 6, lane = t & 63;
  const int quad = lane >> 4, c = lane & 15;
  __shared__ __align__(16) u16 As[2][64][72];
  __shared__ __align__(16) u16 Ws[2][64][72];
  f32x4 acc[4];
#pragma unroll
  for (int ot = 0; ot < 4; ++ot) acc[ot] = (f32x4){0.f, 0.f, 0.f, 0.f};
  const u16* Ab = A + (size_t)b * M * 512;
  const int srow = t >> 2, scol = (t & 3) * 16;

  uint4 ar0, ar1, wr0, wr1, wr2, wr3;

  {
    const uint4* gs = reinterpret_cast<const uint4*>(Ab + (size_t)(m0 + srow) * 512 + scol);
    *reinterpret_cast<uint4*>(&As[0][srow][scol])     = gs[0];
    *reinterpret_cast<uint4*>(&As[0][srow][scol + 8]) = gs[1];
    if (f32) {
      const float* gw = (const float*)W + (size_t)(oo0 + srow) * 512 + scol;
#pragma unroll
      for (int e = 0; e < 16; ++e) Ws[0][srow][scol + e] = f2bs(gw[e]);
    } else {
      const u16* gw = (const u16*)W + (size_t)(oo0 + srow) * 512 + scol;
      *reinterpret_cast<uint4*>(&Ws[0][srow][scol])     = *reinterpret_cast<const uint4*>(gw);
      *reinterpret_cast<uint4*>(&Ws[0][srow][scol + 8]) = *reinterpret_cast<const uint4*>(gw + 8);
    }
    const uint4* gs1 = reinterpret_cast<const uint4*>(Ab + (size_t)(m0 + srow) * 512 + 64 + scol);
    ar0 = gs1[0]; ar1 = gs1[1];
    if (f32) {
      const uint4* gw = reinterpret_cast<const uint4*>(
          (const float*)W + (size_t)(oo0 + srow) * 512 + 64 + scol);
      wr0 = gw[0]; wr1 = gw[1]; wr2 = gw[2]; wr3 = gw[3];
    } else {
      const uint4* gw = reinterpret_cast<const uint4*>(
          (const u16*)W + (size_t)(oo0 + srow) * 512 + 64 + scol);
      wr0 = gw[0]; wr1 = gw[1];
    }
  }

  for (int ki = 0; ki < 8; ++ki) {
    __syncthreads();
    const int bf = ki & 1;

    {
      bf16x8 av = *reinterpret_cast<const bf16x8*>(&As[bf][w * 16 + c][quad * 8]);
#pragma unroll
      for (int ot = 0; ot < 4; ++ot) {
        bf16x8 wv = *reinterpret_cast<const bf16x8*>(&Ws[bf][ot * 16 + c][quad * 8]);
        acc[ot] = __builtin_amdgcn_mfma_f32_16x16x32_bf16(av, wv, acc[ot], 0, 0, 0);
      }
    }

    if (ki + 1 < 8) {
      *reinterpret_cast<uint4*>(&As[bf ^ 1][srow][scol])     = ar0;
      *reinterpret_cast<uint4*>(&As[bf ^ 1][srow][scol + 8]) = ar1;
      if (f32) {
        float tf[16];
        __builtin_memcpy(&tf[0],  &wr0, 16);
        __builtin_memcpy(&tf[4],  &wr1, 16);
        __builtin_memcpy(&tf[8],  &wr2, 16);
        __builtin_memcpy(&tf[12], &wr3, 16);
#pragma unroll
        for (int e = 0; e < 16; ++e) Ws[bf ^ 1][srow][scol + e] = f2bs(tf[e]);
      } else {
        *reinterpret_cast<uint4*>(&Ws[bf ^ 1][srow][scol])     = wr0;
        *reinterpret_cast<uint4*>(&Ws[bf ^ 1][srow][scol + 8]) = wr1;
      }
      if (ki + 2 < 8) {
        const int k0 = (ki + 2) * 64;
        const uint4* gs = reinterpret_cast<const uint4*>(Ab + (size_t)(m0 + srow) * 512 + k0 + scol);
        ar0 = gs[0]; ar1 = gs[1];
        if (f32) {
          const uint4* gw = reinterpret_cast<const uint4*>(
              (const float*)W + (size_t)(oo0 + srow) * 512 + k0 + scol);
          wr0 = gw[0]; wr1 = gw[1]; wr2 = gw[2]; wr3 = gw[3];
        } else {
          const uint4* gw = reinterpret_cast<const uint4*>(
              (const u16*)W + (size_t)(oo0 + srow) * 512 + k0 + scol);
          wr0 = gw[0]; wr1 = gw[1];
        }
      }
    }

    {
      bf16x8 av = *reinterpret_cast<const bf16x8*>(&As[bf][w * 16 + c][32 + quad * 8]);
#pragma unroll
      for (int ot = 0; ot < 4; ++ot) {
        bf16x8 wv = *reinterpret_cast<const bf16x8*>(&Ws[bf][ot * 16 + c][32 + quad * 8]);
        acc[ot] = __builtin_amdgcn_mfma_f32_16x16x32_bf16(av, wv, acc[ot], 0, 0, 0);
      }
    }
  }

#pragma unroll
  for (int ot = 0; ot < 4; ++ot) {
    int o = oo0 + ot * 16 + c;
    float bv = ldf(bias, o, f32);
    int hh = o >> 7, jj = o & 127;
#pragma unroll
    for (int r = 0; r < 4; ++r) {
      int m = m0 + w * 16 + quad * 4 + r;
      u16 val = f2bs(acc[ot][r] + bv);
      if (jj < 64) {
        kb[((size_t)(b * 8 + hh) * M + m) * 64 + jj] = val;
      } else {
        int d = jj & 63;
        v2[((((size_t)(b * 8 + hh) * 16 + (m >> 6)) * 2 + ((m >> 5) & 1)) * 4 + (d >> 4)) * 512
           + (((m >> 3) & 3) * 16 + (d & 15)) * 8 + (m & 7)] = val;
      }
    }
  }
}

// ---------------------------------------------------------------------------
// scores -> top-16 coarse cells -> 64 full-res positions into posb.
// Vectorized score loads (8 x uint4/row); per-wave shfl_xor selection.
// ---------------------------------------------------------------------------
__global__ __launch_bounds__(256) void topk_kernel(
    const float* __restrict__ qsum, const u16* __restrict__ k,
    const float* __restrict__ heat, const void* __restrict__ gumbel,
    int* __restrict__ posb, const int* __restrict__ dtf) {
  const int f32 = *dtf;
  int bh = blockIdx.x, b = bh >> 3, t = threadIdx.x;
  const int lane = t & 63, w = t >> 6;
  __shared__ float qs[64];
  __shared__ float s[1024];
  __shared__ float rv[4];
  __shared__ int   ri[4];
  if (t < 64) qs[t] = qsum[bh * 64 + t];
  __syncthreads();
  for (int j = 0; j < 4; ++j) {
    int m = t + j * 256;
    const uint4* kr = reinterpret_cast<const uint4*>(k + ((size_t)bh * 1024 + m) * 64);
    float dot = 0.f;
#pragma unroll
    for (int v = 0; v < 8; ++v) {
      uint4 kq = kr[v];
      u16 tmp[8];
      *reinterpret_cast<uint4*>(tmp) = kq;
#pragma unroll
      for (int e = 0; e < 8; ++e) dot += qs[v * 8 + e] * bs2f(tmp[e]);
    }
    s[m] = dot * (0.125f / 4096.0f) * (heat[b * 1024 + m] * (1.0f / 2048.0f)) +
           ldf(gumbel, (size_t)bh * 1024 + m, f32);
  }
  __syncthreads();
  for (int it = 0; it < 16; ++it) {
    float bv = -1e30f; int bi = 0x7fffffff;
    for (int j = 0; j < 4; ++j) {
      int m = t + j * 256; float vv = s[m];
      if (vv > bv || (vv == bv && m < bi)) { bv = vv; bi = m; }
    }
#pragma unroll
    for (int off = 1; off < 64; off <<= 1) {
      float ov = __shfl_xor(bv, off, 64);
      int   oi = __shfl_xor(bi, off, 64);
      if (ov > bv || (ov == bv && oi < bi)) { bv = ov; bi = oi; }
    }
    if (lane == 0) { rv[w] = bv; ri[w] = bi; }
    __syncthreads();
    if (t == 0) {
      float fv = rv[0]; int fi = ri[0];
#pragma unroll
      for (int ww = 1; ww < 4; ++ww)
        if (rv[ww] > fv || (rv[ww] == fv && ri[ww] < fi)) { fv = rv[ww]; fi = ri[ww]; }
      s[fi] = -1e30f;
      int hy = (fi >> 5) * 2, wx = (fi & 31) * 2;
      posb[bh * 64 + it]      = hy * 64 + wx;
      posb[bh * 64 + 16 + it] = hy * 64 + wx + 1;
      posb[bh * 64 + 32 + it] = (hy + 1) * 64 + wx;
      posb[bh * 64 + 48 + it] = (hy + 1) * 64 + wx + 1;
    }
    __syncthreads();
  }
}

// ---------------------------------------------------------------------------
// gather_kv as MFMA GEMM (r14-proven named-scalar dbuf, 1 barrier/K-step).
// ---------------------------------------------------------------------------
__global__ __launch_bounds__(256) void gather_kv_mfma(
    const u16* __restrict__ xT, const void* __restrict__ kv_w,
    const void* __restrict__ kv_b, const int* __restrict__ posb,
    u16* __restrict__ tkb, u16* __restrict__ tvTb,
    const int* __restrict__ dtf) {
  const int f32 = *dtf;
  const int bh = blockIdx.x, b = bh >> 3, h = bh & 7;
  const int half = blockIdx.y;
  const int t = threadIdx.x, w = t >> 6, lane = t & 63;
  const int quad = lane >> 4, c = lane & 15;
  __shared__ int pos[64];
  __shared__ __align__(16) u16 As[2][64][72];
  __shared__ __align__(16) u16 Ws[2][64][72];
  if (t < 64) pos[t] = posb[bh * 64 + t];
  __syncthreads();
  const int obase = h * 128 + half * 64;
  const int srow = t >> 2, scol = (t & 3) * 16;
  const int arow = pos[srow];
  const u16* Ab = xT + ((size_t)b * 4096 + arow) * 512;
  f32x4 acc[4];
#pragma unroll
  for (int ot = 0; ot < 4; ++ot) acc[ot] = (f32x4){0.f, 0.f, 0.f, 0.f};

  uint4 ar0, ar1, wr0, wr1, wr2, wr3;

  {
    const uint4* gs = reinterpret_cast<const uint4*>(Ab + scol);
    *reinterpret_cast<uint4*>(&As[0][srow][scol])     = gs[0];
    *reinterpret_cast<uint4*>(&As[0][srow][scol + 8]) = gs[1];
    if (f32) {
      const float* gw = (const float*)kv_w + (size_t)(obase + srow) * 512 + scol;
#pragma unroll
      for (int e = 0; e < 16; ++e) Ws[0][srow][scol + e] = f2bs(gw[e]);
    } else {
      const u16* gw = (const u16*)kv_w + (size_t)(obase + srow) * 512 + scol;
      *reinterpret_cast<uint4*>(&Ws[0][srow][scol])     = *reinterpret_cast<const uint4*>(gw);
      *reinterpret_cast<uint4*>(&Ws[0][srow][scol + 8]) = *reinterpret_cast<const uint4*>(gw + 8);
    }
    const uint4* gs1 = reinterpret_cast<const uint4*>(Ab + 64 + scol);
    ar0 = gs1[0]; ar1 = gs1[1];
    if (f32) {
      const uint4* gw = reinterpret_cast<const uint4*>(
          (const float*)kv_w + (size_t)(obase + srow) * 512 + 64 + scol);
      wr0 = gw[0]; wr1 = gw[1]; wr2 = gw[2]; wr3 = gw[3];
    } else {
      const uint4* gw = reinterpret_cast<const uint4*>(
          (const u16*)kv_w + (size_t)(obase + srow) * 512 + 64 + scol);
      wr0 = gw[0]; wr1 = gw[1];
    }
  }

  for (int ki = 0; ki < 8; ++ki) {
    __syncthreads();
    const int bf = ki & 1;

    {
      bf16x8 av = *reinterpret_cast<const bf16x8*>(&As[bf][w * 16 + c][quad * 8]);
#pragma unroll
      for (int ot = 0; ot < 4; ++ot) {
        bf16x8 wv = *reinterpret_cast<const bf16x8*>(&Ws[bf][ot * 16 + c][quad * 8]);
        acc[ot] = __builtin_amdgcn_mfma_f32_16x16x32_bf16(av, wv, acc[ot], 0, 0, 0);
      }
    }

    if (ki + 1 < 8) {
      *reinterpret_cast<uint4*>(&As[bf ^ 1][srow][scol])     = ar0;
      *reinterpret_cast<uint4*>(&As[bf ^ 1][srow][scol + 8]) = ar1;
      if (f32) {
        float tf[16];
        __builtin_memcpy(&tf[0],  &wr0, 16);
        __builtin_memcpy(&tf[4],  &wr1, 16);
        __builtin_memcpy(&tf[8],  &wr2, 16);
        __builtin_memcpy(&tf[12], &wr3, 16);
#pragma unroll
        for (int e = 0; e < 16; ++e) Ws[bf ^ 1][srow][scol + e] = f2bs(tf[e]);
      } else {
        *reinterpret_cast<uint4*>(&Ws[bf ^ 1][srow][scol])     = wr0;
        *reinterpret_cast<uint4*>(&Ws[bf ^ 1][srow][scol + 8]) = wr1;
      }
      if (ki + 2 < 8) {
        const int k0 = (ki + 2) * 64;
        const uint4* gs = reinterpret_cast<const uint4*>(Ab + k0 + scol);
        ar0 = gs[0]; ar1 = gs[1];
        if (f32) {
          const uint4* gw = reinterpret_cast<const uint4*>(
              (const float*)kv_w + (size_t)(obase + srow) * 512 + k0 + scol);
          wr0 = gw[0]; wr1 = gw[1]; wr2 = gw[2]; wr3 = gw[3];
        } else {
          const uint4* gw = reinterpret_cast<const uint4*>(
              (const u16*)kv_w + (size_t)(obase + srow) * 512 + k0 + scol);
          wr0 = gw[0]; wr1 = gw[1];
        }
      }
    }

    {
      bf16x8 av = *reinterpret_cast<const bf16x8*>(&As[bf][w * 16 + c][32 + quad * 8]);
#pragma unroll
      for (int ot = 0; ot < 4; ++ot) {
        bf16x8 wv = *reinterpret_cast<const bf16x8*>(&Ws[bf][ot * 16 + c][32 + quad * 8]);
        acc[ot] = __builtin_amdgcn_mfma_f32_16x16x32_bf16(av, wv, acc[ot], 0, 0, 0);
      }
    }
  }

#pragma unroll
  for (int ot = 0; ot < 4; ++ot) {
    int d = ot * 16 + c;
    float bv = ldf(kv_b, obase + d, f32);
#pragma unroll
    for (int r = 0; r < 4; ++r) {
      int m = w * 16 + quad * 4 + r;
      u16 val = f2bs(acc[ot][r] + bv);
      if (half) tvTb[((size_t)bh * 64 + d) * 64 + m] = val;
      else      tkb[((size_t)bh * 64 + m) * 64 + d] = val;
    }
  }
}

// ---------------------------------------------------------------------------
// depthwise 7x7 conv on v (v2 swizzled layout) -> vpe bf16 (strip structure:
// 4-row column strip per thread, weights in regs, row segments reused across
// output rows; DS reads/thread 392 -> ~119).
// ---------------------------------------------------------------------------
__global__ __launch_bounds__(256) void dwconv_kernel(
    const u16* __restrict__ v2, const void* __restrict__ pe_w,
    const void* __restrict__ pe_b, u16* __restrict__ vpe,
    const int* __restrict__ dtf) {
  const int f32 = *dtf;
  int bc = blockIdx.x;
  int b = bc >> 9, c = bc & 511;
  int h = c >> 6, d = c & 63;
  int dt = d >> 4, cc = d & 15;
  int t = threadIdx.x;
  __shared__ float img[1024];
  __shared__ float wts[49];
  if (t < 128) {
    int ch = t >> 3, s = (t >> 2) & 1, q2 = t & 3;
    const u16* src = v2 + ((((size_t)(b * 8 + h) * 16 + ch) * 2 + s) * 4 + dt) * 512
                        + (q2 * 16 + cc) * 8;
    uint4 v4 = *reinterpret_cast<const uint4*>(src);
    u16 tmp[8];
    *reinterpret_cast<uint4*>(tmp) = v4;
#pragma unroll
    for (int e = 0; e < 8; ++e) img[t * 8 + e] = bs2f(tmp[e]);
  }
  if (t < 49) wts[t] = ldf(pe_w, c * 49 + t, f32);
  float bias = ldf(pe_b, c, f32);
  __syncthreads();

  float wreg[49];
#pragma unroll
  for (int i = 0; i < 49; ++i) wreg[i] = wts[i];

  const int x = t & 31, y0 = (t >> 5) * 4;
  float acc[4] = {0.f, 0.f, 0.f, 0.f};
#pragma unroll
  for (int r = 0; r < 10; ++r) {
    int yy = y0 - 3 + r;
    if ((unsigned)yy >= 32u) continue;
    float rr[7];
#pragma unroll
    for (int j = 0; j < 7; ++j) {
      int xc = x - 3 + j;
      rr[j] = ((unsigned)xc < 32u) ? img[yy * 32 + xc] : 0.f;
    }
#pragma unroll
    for (int p = 0; p < 4; ++p) {
      int ky = r - p;                 // yy = (y0+p) + ky - 3
      if (ky < 0 || ky > 6) continue;
      float s2 = 0.f;
#pragma unroll
      for (int j = 0; j < 7; ++j) s2 += rr[j] * wreg[ky * 7 + j];
      acc[p] += s2;
    }
  }
#pragma unroll
  for (int p = 0; p < 4; ++p)
    vpe[(size_t)bc * 1024 + (y0 + p) * 32 + x] = f2bs(acc[p] + bias);
}

// ---------------------------------------------------------------------------
// FUSED coarse+fine attention (r6/r10 structure — proven 47us local optimum).
// 64-row blocks (grid 64 x 16bh, 4 blocks/CU, 16 waves/CU); K LDS-dbuf with
// register prefetch (1 barrier/chunk); V register-direct from v2 (coalesced,
// in-chunk issue distance). UNCHANGED.
// ---------------------------------------------------------------------------
__global__ __launch_bounds__(256, 4) void attn_fused(
    const u16* __restrict__ q, const u16* __restrict__ k,
    const u16* __restrict__ v2, const u16* __restrict__ tkb,
    const u16* __restrict__ tvTb, const u16* __restrict__ gwb,
    const float* __restrict__ gbf, const u16* __restrict__ vpe,
    u16* __restrict__ xsT) {
  const int bh = blockIdx.y, b = bh >> 3, h = bh & 7;
  const int bx = blockIdx.x;          // output image row y = bx
  const int n0 = bx * 64;
  const int t = threadIdx.x, w = t >> 6, lane = t & 63;
  const int quad = lane >> 4, c = lane & 15;

  __shared__ __align__(16) u16 lds[13824];   // 27.6 KB union
  u16* Ks = lds;              // [2][64][72] K double-buffer
  u16* Ps = lds + 9216;       // [4][16][72] per-wave P tiles

  // ---- phase A: coarse ----
  bf16x8 bq[2];
  {
    const u16* qr = q + ((size_t)bh * 4096 + n0 + w * 16 + c) * 64;
    bq[0] = *reinterpret_cast<const bf16x8*>(qr + quad * 8);
    bq[1] = *reinterpret_cast<const bf16x8*>(qr + 32 + quad * 8);
  }
  f32x4 po[4];
#pragma unroll
  for (int dt = 0; dt < 4; ++dt) po[dt] = (f32x4){0.f, 0.f, 0.f, 0.f};
  float sume = 0.f;

  const u16* kbase = k + (size_t)bh * 65536;
  const u16* v2base = v2 + (size_t)bh * 65536;
  const int srow = t >> 2, scol = (t & 3) * 16;

  uint4 kr0, kr1;
  {
    // chunk 0 staged directly into buf 0
    const u16* gk = kbase + (size_t)srow * 64 + scol;
    kr0 = *reinterpret_cast<const uint4*>(gk);
    kr1 = *reinterpret_cast<const uint4*>(gk + 8);
    *reinterpret_cast<uint4*>(&Ks[srow * 72 + scol])     = kr0;
    *reinterpret_cast<uint4*>(&Ks[srow * 72 + scol + 8]) = kr1;
    // prefetch chunk 1 into regs
    const u16* gk1 = kbase + (size_t)(64 + srow) * 64 + scol;
    kr0 = *reinterpret_cast<const uint4*>(gk1);
    kr1 = *reinterpret_cast<const uint4*>(gk1 + 8);
  }

  for (int ch = 0; ch < 16; ++ch) {
    __syncthreads();
    const int buf = ch & 1;

    // V fragments: coalesced register-direct loads (consumed at PV)
    bf16x8 av[4][2];
    {
      const u16* v2c = v2base + (size_t)ch * 4096;
#pragma unroll
      for (int dt = 0; dt < 4; ++dt) {
        av[dt][0] = *reinterpret_cast<const bf16x8*>(v2c + dt * 512 + lane * 8);
        av[dt][1] = *reinterpret_cast<const bf16x8*>(v2c + 2048 + dt * 512 + lane * 8);
      }
    }

    // QK from LDS K buffer
    f32x4 st[4];
#pragma unroll
    for (int mt = 0; mt < 4; ++mt) {
      const u16* krow = &Ks[buf * 4608 + (mt * 16 + c) * 72];
      bf16x8 ak0 = *reinterpret_cast<const bf16x8*>(krow + quad * 8);
      bf16x8 ak1 = *reinterpret_cast<const bf16x8*>(krow + 32 + quad * 8);
      f32x4 acc = (f32x4){0.f, 0.f, 0.f, 0.f};
      acc = __builtin_amdgcn_mfma_f32_16x16x32_bf16(ak0, bq[0], acc, 0, 0, 0);
      acc = __builtin_amdgcn_mfma_f32_16x16x32_bf16(ak1, bq[1], acc, 0, 0, 0);
      st[mt] = acc;
    }

    // stage prefetched K into other buffer; prefetch ch+2
    if (ch + 1 < 16) {
      *reinterpret_cast<uint4*>(&Ks[(buf ^ 1) * 4608 + srow * 72 + scol])     = kr0;
      *reinterpret_cast<uint4*>(&Ks[(buf ^ 1) * 4608 + srow * 72 + scol + 8]) = kr1;
      if (ch + 2 < 16) {
        const u16* gk = kbase + (size_t)((ch + 2) * 64 + srow) * 64 + scol;
        kr0 = *reinterpret_cast<const uint4*>(gk);
        kr1 = *reinterpret_cast<const uint4*>(gk + 8);
      }
    }

    // softmax numerator (q pre-scaled; raw exp)
    float cs = 0.f;
    u16* psw = &Ps[(w * 16 + c) * 72];
#pragma unroll
    for (int mt = 0; mt < 4; ++mt) {
      float e0 = __expf(st[mt][0]);
      float e1 = __expf(st[mt][1]);
      float e2 = __expf(st[mt][2]);
      float e3 = __expf(st[mt][3]);
      cs += (e0 + e1) + (e2 + e3);
      ushort4 pw;
      pw.x = f2bs(e0); pw.y = f2bs(e1); pw.z = f2bs(e2); pw.w = f2bs(e3);
      *reinterpret_cast<ushort4*>(psw + mt * 16 + quad * 4) = pw;
    }
    cs += __shfl_xor(cs, 16, 64);
    cs += __shfl_xor(cs, 32, 64);
    sume += cs;

    // PV
#pragma unroll
    for (int s = 0; s < 2; ++s) {
      bf16x8 bp = *reinterpret_cast<const bf16x8*>(psw + s * 32 + quad * 8);
#pragma unroll
      for (int dt = 0; dt < 4; ++dt) {
        po[dt] = __builtin_amdgcn_mfma_f32_16x16x32_bf16(av[dt][s], bp, po[dt], 0, 0, 0);
      }
    }
  }

  __syncthreads();  // phase A LDS dead; repartition
  u16* fus = lds;                       // [4][16][136]
  u16* vl  = lds + 8704;                // [2][64][36]
  float* gbl = (float*)(lds + 13312);   // [64]

  // block-uniform bilinear y setup (all rows of this block have y = bx)
  const int ym = bx >> 1;
  int r0_, r1_; float wy0, wy1;
  if ((bx & 1) == 0) { r0_ = ym > 0 ? ym - 1 : 0; r1_ = ym; wy0 = 0.25f; wy1 = 0.75f; }
  else               { r0_ = ym; r1_ = ym < 31 ? ym + 1 : 31; wy0 = 0.75f; wy1 = 0.25f; }

  for (int idx = t; idx < 512; idx += 256) {
    int seg = idx & 3, ch2 = (idx >> 2) & 63, rr = idx >> 8;
    int vrow = rr ? r1_ : r0_;
    const uint4 v4 = *reinterpret_cast<const uint4*>(
        vpe + ((size_t)(b * 512 + h * 64 + ch2)) * 1024 + vrow * 32 + seg * 8);
    u16* dst = &vl[(rr * 64 + ch2) * 36 + seg * 8];
    uint2 lo, hi;
    lo.x = v4.x; lo.y = v4.y; hi.x = v4.z; hi.y = v4.w;
    *reinterpret_cast<uint2*>(dst)     = lo;
    *reinterpret_cast<uint2*>(dst + 4) = hi;
  }
  if (t < 64) gbl[t] = gbf[t];
  __syncthreads();

  // ---- phase B: fine, per wave (16 q-rows each) ----
  u16* fusw = &fus[(w * 16 + c) * 136];
  f32x4 st2[4];
#pragma unroll
  for (int mt = 0; mt < 4; ++mt) {
    f32x4 acc = (f32x4){0.f, 0.f, 0.f, 0.f};
#pragma unroll
    for (int s = 0; s < 2; ++s) {
      bf16x8 ak = *reinterpret_cast<const bf16x8*>(
          &tkb[((size_t)bh * 64 + mt * 16 + c) * 64 + s * 32 + quad * 8]);
      acc = __builtin_amdgcn_mfma_f32_16x16x32_bf16(ak, bq[s], acc, 0, 0, 0);
    }
    st2[mt] = acc;
  }
  float sume2 = 0.f;
#pragma unroll
  for (int mt = 0; mt < 4; ++mt) {
    float e0 = __expf(st2[mt][0]);
    float e1 = __expf(st2[mt][1]);
    float e2 = __expf(st2[mt][2]);
    float e3 = __expf(st2[mt][3]);
    sume2 += (e0 + e1) + (e2 + e3);
    ushort4 pw;
    pw.x = f2bs(e0); pw.y = f2bs(e1); pw.z = f2bs(e2); pw.w = f2bs(e3);
    *reinterpret_cast<ushort4*>(fusw + mt * 16 + quad * 4) = pw;
  }
  sume2 += __shfl_xor(sume2, 16, 64);
  sume2 += __shfl_xor(sume2, 32, 64);
  float inv2 = 1.0f / sume2;

  f32x4 po2[4];
#pragma unroll
  for (int dt = 0; dt < 4; ++dt) po2[dt] = (f32x4){0.f, 0.f, 0.f, 0.f};
#pragma unroll
  for (int s = 0; s < 2; ++s) {
    bf16x8 bp = *reinterpret_cast<const bf16x8*>(fusw + s * 32 + quad * 8);
#pragma unroll
    for (int dt = 0; dt < 4; ++dt) {
      bf16x8 av = *reinterpret_cast<const bf16x8*>(
          &tvTb[((size_t)bh * 64 + dt * 16 + c) * 64 + s * 32 + quad * 8]);
      po2[dt] = __builtin_amdgcn_mfma_f32_16x16x32_bf16(av, bp, po2[dt], 0, 0, 0);
    }
  }

  // fusion [coarse | refined]
  float invc = 1.0f / sume;
#pragma unroll
  for (int dt = 0; dt < 4; ++dt) {
    ushort4 cw, rw;
    cw.x = f2bs(po[dt][0] * invc); cw.y = f2bs(po[dt][1] * invc);
    cw.z = f2bs(po[dt][2] * invc); cw.w = f2bs(po[dt][3] * invc);
    rw.x = f2bs(po2[dt][0] * inv2); rw.y = f2bs(po2[dt][1] * inv2);
    rw.z = f2bs(po2[dt][2] * inv2); rw.w = f2bs(po2[dt][3] * inv2);
    *reinterpret_cast<ushort4*>(fusw + dt * 16 + quad * 4)      = cw;
    *reinterpret_cast<ushort4*>(fusw + 64 + dt * 16 + quad * 4) = rw;
  }

  // gate MFMA (K=128), A-frags from global gwb
  f32x4 ga[4];
#pragma unroll
  for (int ot = 0; ot < 4; ++ot) ga[ot] = (f32x4){0.f, 0.f, 0.f, 0.f};
#pragma unroll
  for (int s = 0; s < 4; ++s) {
    bf16x8 bf = *reinterpret_cast<const bf16x8*>(fusw + s * 32 + quad * 8);
#pragma unroll
    for (int ot = 0; ot < 4; ++ot) {
      bf16x8 ag = *reinterpret_cast<const bf16x8*>(
          gwb + (ot * 16 + c) * 128 + s * 32 + quad * 8);
      ga[ot] = __builtin_amdgcn_mfma_f32_16x16x32_bf16(ag, bf, ga[ot], 0, 0, 0);
    }
  }

  // combine + bilinear; overwrite fus rows 0..63 (same-lane read->write)
  const int x = w * 16 + c;              // x coordinate of this q-row
  int jx = x >> 1, x0, x1; float wx0, wx1;
  if ((x & 1) == 0) { x0 = (jx > 0) ? jx - 1 : 0; x1 = jx; wx0 = 0.25f; wx1 = 0.75f; }
  else              { x0 = jx; x1 = (jx < 31) ? jx + 1 : 31; wx0 = 0.75f; wx1 = 0.25f; }
#pragma unroll
  for (int dt = 0; dt < 4; ++dt) {
    ushort4 ow;
    u16 tmp[4];
#pragma unroll
    for (int r = 0; r < 4; ++r) {
      int row = dt * 16 + quad * 4 + r;
      float ref = po2[dt][r] * inv2;
      float coar = bs2f(fusw[row]);
      float g = 1.0f / (1.0f + __expf(-(ga[dt][r] + gbl[row])));
      float vv = wy0 * (wx0 * bs2f(vl[row * 36 + x0]) +
                        wx1 * bs2f(vl[row * 36 + x1])) +
                 wy1 * (wx0 * bs2f(vl[(64 + row) * 36 + x0]) +
                        wx1 * bs2f(vl[(64 + row) * 36 + x1]));
      tmp[r] = f2bs(g * ref + (1.0f - g) * coar + vv);
    }
    ow.x = tmp[0]; ow.y = tmp[1]; ow.z = tmp[2]; ow.w = tmp[3];
    *reinterpret_cast<ushort4*>(fusw + dt * 16 + quad * 4) = ow;
  }

  // store n-major rows (same-wave cross-lane reads, in-order DS)
  {
    int nl = lane >> 2, cs2 = (lane & 3) * 16;
    const u16* srcrow = &fus[(w * 16 + nl) * 136 + cs2];
    u16* dst = xsT + ((size_t)b * 4096 + n0 + w * 16 + nl) * 512 + h * 64 + cs2;
    *reinterpret_cast<uint4*>(dst)     = *reinterpret_cast<const uint4*>(srcrow);
    *reinterpret_cast<uint4*>(dst + 8) = *reinterpret_cast<const uint4*>(srcrow + 8);
  }
}

extern "C" void kernel_launch(void* const* d_in, const int* in_sizes, int n_in,
                              void* d_out, int out_size, void* d_ws, size_t ws_size,
                              hipStream_t stream) {
  const void* x    = d_in[0];
  const void* up   = d_in[1];
  const void* gum  = d_in[2];
  const void* q_w  = d_in[3];
  const void* q_b  = d_in[4];
  const void* kv_w = d_in[5];
  const void* kv_b = d_in[6];
  const void* p_w  = d_in[7];
  const void* p_b  = d_in[8];
  const void* pe_w = d_in[9];
  const void* pe_b = d_in[10];
  const void* g_w  = d_in[11];
  const void* g_b  = d_in[12];

  float* ws    = (float*)d_ws;
  int*   dtf   = (int*)ws;                   // 16 f
  float* qsum  = ws + 16;                    // 1024 f
  float* heat  = qsum + 1024;                // 2048 f
  int*   posb  = (int*)(heat + 2048);        // 1024 ints
  float* gbf   = (float*)(posb + 1024);      // 64
  u16*   gwb   = (u16*)(gbf + 64);           // 8192 u16
  u16*   tkb   = gwb + 8192;                 // 65536
  u16*   tvTb  = tkb + 65536;                // 65536
  u16*   qb    = tvTb + 65536;               // 4M
  u16*   kb    = qb + 4194304;               // 1M
  u16*   v2b   = kb + 1048576;               // 1M   (swizzled V)
  u16*   xT    = v2b + 1048576;              // 4M
  u16*   upT   = xT + 4194304;               // 1M
  u16*   xsT   = upT + 1048576;              // 4M
  u16*   vpe   = xsT + 4194304;              // 1M   (~26 MB total)

  dim3 blk(256);
  hipMemsetAsync(ws, 0, (16 + 1024 + 2048) * 4, stream);
  detect_dtype<<<dim3(64), blk, 0, stream>>>((const uint4*)x, dtf);
  prep_gate<<<dim3(1), blk, 0, stream>>>(g_w, g_b, gwb, gbf, dtf);
  transpose_bf16<<<dim3(64, 8, 2), blk, 0, stream>>>(x, xT, 4096, heat, dtf);
  transpose_bf16<<<dim3(16, 8, 2), blk, 0, stream>>>(up, upT, 1024, nullptr, dtf);
  gemm128<0><<<dim3(32, 4, 2), blk, 0, stream>>>(xT, q_w, q_b, qb, nullptr, qsum, 4096, dtf);
  gemm_kv<<<dim3(16, 16, 2), blk, 0, stream>>>(upT, kv_w, kv_b, kb, v2b, 1024, dtf);
  topk_kernel<<<dim3(16), blk, 0, stream>>>(qsum, kb, heat, gum, posb, dtf);
  gather_kv_mfma<<<dim3(16, 2), blk, 0, stream>>>(xT, kv_w, kv_b, posb, tkb, tvTb, dtf);
  dwconv_kernel<<<dim3(1024), blk, 0, stream>>>(v2b, pe_w, pe_b, vpe, dtf);
  attn_fused<<<dim3(64, 16), blk, 0, stream>>>(qb, kb, v2b, tkb, tvTb, gwb, gbf, vpe, xsT);
  gemm128<3><<<dim3(32, 4, 2), blk, 0, stream>>>(xsT, p_w, p_b, nullptr, d_out, nullptr, 4096, dtf);
}

// Round 16
// 235.748 us; speedup vs baseline: 1.0195x; 1.0195x over previous
//
#include <hip/hip_runtime.h>
#include <hip/hip_bf16.h>
#include <cstdint>

typedef __hip_bfloat16 bf16;
typedef unsigned short u16;
typedef __attribute__((ext_vector_type(8))) short bf16x8;
typedef __attribute__((ext_vector_type(4))) float f32x4;

static __device__ __forceinline__ float bs2f(u16 s) {
  unsigned int u = ((unsigned int)s) << 16;
  float f;
  __builtin_memcpy(&f, &u, 4);
  return f;
}
static __device__ __forceinline__ u16 f2bs(float f) {
  bf16 h = __float2bfloat16(f);
  u16 s;
  __builtin_memcpy(&s, &h, 2);
  return s;
}
static __device__ __forceinline__ float ldf(const void* p, size_t i, int f32) {
  return f32 ? ((const float*)p)[i] : bs2f(((const u16*)p)[i]);
}

// ---------------------------------------------------------------------------
// dtype detection on a 256 KB sample of x.
// ---------------------------------------------------------------------------
__global__ __launch_bounds__(256) void detect_dtype(const uint4* __restrict__ xs,
                                                    int* __restrict__ flag) {
  int i = blockIdx.x * 256 + threadIdx.x;
  uint4 v = xs[i];
  bool hit = false;
#pragma unroll
  for (int j = 0; j < 4; ++j) {
    unsigned w = (j == 0) ? v.x : (j == 1) ? v.y : (j == 2) ? v.z : v.w;
    if ((w & 0x7F80u) == 0x7F80u) hit = true;
    if ((w & 0x7F800000u) == 0x7F800000u) hit = true;
  }
  unsigned long long mask = __ballot(hit);
  if (mask != 0ull && (threadIdx.x & 63) == 0) atomicOr(flag, 1);
}

// one-time gate weights conversion -> bf16 gwb[64][128], f32 gbf[64]
__global__ __launch_bounds__(256) void prep_gate(
    const void* __restrict__ gate_w, const void* __restrict__ gate_b,
    u16* __restrict__ gwb, float* __restrict__ gbf,
    const int* __restrict__ dtf) {
  const int f32 = *dtf;
  int t = threadIdx.x;
  for (int i = t; i < 8192; i += 256)
    gwb[i] = f32 ? f2bs(((const float*)gate_w)[i]) : ((const u16*)gate_w)[i];
  if (t < 64) gbf[t] = ldf(gate_b, t, f32);
}

// ---------------------------------------------------------------------------
// transpose [b][c=512][N] -> [b][N][512] bf16; optional fused heat partials.
// ---------------------------------------------------------------------------
__global__ __launch_bounds__(256) void transpose_bf16(
    const void* __restrict__ src, u16* __restrict__ dst, int N,
    float* __restrict__ heat, const int* __restrict__ dtf) {
  const int f32 = *dtf;
  const int b = blockIdx.z, n0 = blockIdx.x * 64, c0 = blockIdx.y * 64;
  const int t = threadIdx.x;
  __shared__ __align__(16) u16 tile[64][72];
#pragma unroll
  for (int j = 0; j < 2; ++j) {
    int cc = (t >> 3) + j * 32;
    int nn = (t & 7) * 8;
    u16 tmp[8];
    if (f32) {
      const float* s4 = (const float*)src + ((size_t)(b * 512 + c0 + cc)) * N + n0 + nn;
#pragma unroll
      for (int u = 0; u < 8; ++u) tmp[u] = f2bs(s4[u]);
    } else {
      *reinterpret_cast<uint4*>(tmp) = *reinterpret_cast<const uint4*>(
          (const u16*)src + ((size_t)(b * 512 + c0 + cc)) * N + n0 + nn);
    }
    *reinterpret_cast<uint4*>(&tile[cc][nn]) = *reinterpret_cast<const uint4*>(tmp);
  }
  __syncthreads();
  if (heat != nullptr && t < 32) {
    float s = 0.f;
#pragma unroll 8
    for (int cc = 0; cc < 64; ++cc)
      s += bs2f(tile[cc][2 * t]) + bs2f(tile[cc][2 * t + 1]);
    int y = blockIdx.x;
    atomicAdd(&heat[b * 1024 + (y >> 1) * 32 + t], s);
  }
#pragma unroll
  for (int j = 0; j < 2; ++j) {
    int nn = (t >> 3) + j * 32;
    int cc0 = (t & 7) * 8;
    u16 tmp[8];
#pragma unroll
    for (int u = 0; u < 8; ++u) tmp[u] = tile[cc0 + u][nn];
    *reinterpret_cast<uint4*>(&dst[((size_t)b * N + n0 + nn) * 512 + c0 + cc0]) =
        *reinterpret_cast<const uint4*>(tmp);
  }
}

// ---------------------------------------------------------------------------
// 128m x 64o MFMA conv1x1 GEMM (r13-proven: LDS dbuf + register prefetch in
// NAMED uint4 SCALARS, straight-line. 1 barrier/K-step; store-prefetch sits
// between the two ks halves. Grid (32,8,2) = 2 blocks/CU: named-scalar dbuf
// + cross-block TLP is the measured sweet spot (r15's 1-block/CU 128-o-tile
// widening regressed ~5.5us). MODE 0 (q): outputs scaled by 0.125.
// ---------------------------------------------------------------------------
template<int MODE>
__global__ __launch_bounds__(256) void gemm128(
    const u16* __restrict__ A, const void* __restrict__ W,
    const void* __restrict__ bias, u16* __restrict__ o0,
    void* __restrict__ ob, float* __restrict__ qsum, int M,
    const int* __restrict__ dtf) {
  const int f32 = *dtf;
  const int b = blockIdx.z, m0 = blockIdx.x * 128, oo0 = blockIdx.y * 64;
  const int t = threadIdx.x, w = t >> 6, lane = t & 63;
  const int quad = lane >> 4, c = lane & 15;
  __shared__ __align__(16) u16 As[2][128][72];
  __shared__ __align__(16) u16 Ws[2][64][72];
  f32x4 acc[2][4];
#pragma unroll
  for (int nt = 0; nt < 2; ++nt)
#pragma unroll
    for (int ot = 0; ot < 4; ++ot) acc[nt][ot] = (f32x4){0.f, 0.f, 0.f, 0.f};
  const u16* Ab = A + (size_t)b * M * 512;
  const int arow = t >> 1, acol = (t & 1) * 32;
  const int wrow = t >> 2, wcol = (t & 3) * 16;

  uint4 ar0, ar1, ar2, ar3, wr0, wr1, wr2, wr3;

  {
    const uint4* gs = reinterpret_cast<const uint4*>(Ab + (size_t)(m0 + arow) * 512 + acol);
    uint4* ad = reinterpret_cast<uint4*>(&As[0][arow][acol]);
    ad[0] = gs[0]; ad[1] = gs[1]; ad[2] = gs[2]; ad[3] = gs[3];
    if (f32) {
      const float* gw = (const float*)W + (size_t)(oo0 + wrow) * 512 + wcol;
#pragma unroll
      for (int e = 0; e < 16; ++e) Ws[0][wrow][wcol + e] = f2bs(gw[e]);
    } else {
      const u16* gw = (const u16*)W + (size_t)(oo0 + wrow) * 512 + wcol;
      *reinterpret_cast<uint4*>(&Ws[0][wrow][wcol])     = *reinterpret_cast<const uint4*>(gw);
      *reinterpret_cast<uint4*>(&Ws[0][wrow][wcol + 8]) = *reinterpret_cast<const uint4*>(gw + 8);
    }
    const uint4* gs1 = reinterpret_cast<const uint4*>(Ab + (size_t)(m0 + arow) * 512 + 64 + acol);
    ar0 = gs1[0]; ar1 = gs1[1]; ar2 = gs1[2]; ar3 = gs1[3];
    if (f32) {
      const uint4* gw = reinterpret_cast<const uint4*>(
          (const float*)W + (size_t)(oo0 + wrow) * 512 + 64 + wcol);
      wr0 = gw[0]; wr1 = gw[1]; wr2 = gw[2]; wr3 = gw[3];
    } else {
      const uint4* gw = reinterpret_cast<const uint4*>(
          (const u16*)W + (size_t)(oo0 + wrow) * 512 + 64 + wcol);
      wr0 = gw[0]; wr1 = gw[1];
    }
  }

  for (int ki = 0; ki < 8; ++ki) {
    __syncthreads();
    const int bf = ki & 1;

    // ks = 0 half
    {
      bf16x8 av0 = *reinterpret_cast<const bf16x8*>(&As[bf][w * 32 + c][quad * 8]);
      bf16x8 av1 = *reinterpret_cast<const bf16x8*>(&As[bf][w * 32 + 16 + c][quad * 8]);
#pragma unroll
      for (int ot = 0; ot < 4; ++ot) {
        bf16x8 wv = *reinterpret_cast<const bf16x8*>(&Ws[bf][ot * 16 + c][quad * 8]);
        if (MODE == 3) {
          acc[0][ot] = __builtin_amdgcn_mfma_f32_16x16x32_bf16(wv, av0, acc[0][ot], 0, 0, 0);
          acc[1][ot] = __builtin_amdgcn_mfma_f32_16x16x32_bf16(wv, av1, acc[1][ot], 0, 0, 0);
        } else {
          acc[0][ot] = __builtin_amdgcn_mfma_f32_16x16x32_bf16(av0, wv, acc[0][ot], 0, 0, 0);
          acc[1][ot] = __builtin_amdgcn_mfma_f32_16x16x32_bf16(av1, wv, acc[1][ot], 0, 0, 0);
        }
      }
    }

    if (ki + 1 < 8) {
      uint4* ad = reinterpret_cast<uint4*>(&As[bf ^ 1][arow][acol]);
      ad[0] = ar0; ad[1] = ar1; ad[2] = ar2; ad[3] = ar3;
      if (f32) {
        float tf[16];
        __builtin_memcpy(&tf[0],  &wr0, 16);
        __builtin_memcpy(&tf[4],  &wr1, 16);
        __builtin_memcpy(&tf[8],  &wr2, 16);
        __builtin_memcpy(&tf[12], &wr3, 16);
#pragma unroll
        for (int e = 0; e < 16; ++e) Ws[bf ^ 1][wrow][wcol + e] = f2bs(tf[e]);
      } else {
        *reinterpret_cast<uint4*>(&Ws[bf ^ 1][wrow][wcol])     = wr0;
        *reinterpret_cast<uint4*>(&Ws[bf ^ 1][wrow][wcol + 8]) = wr1;
      }
      if (ki + 2 < 8) {
        const int k0 = (ki + 2) * 64;
        const uint4* gs = reinterpret_cast<const uint4*>(Ab + (size_t)(m0 + arow) * 512 + k0 + acol);
        ar0 = gs[0]; ar1 = gs[1]; ar2 = gs[2]; ar3 = gs[3];
        if (f32) {
          const uint4* gw = reinterpret_cast<const uint4*>(
              (const float*)W + (size_t)(oo0 + wrow) * 512 + k0 + wcol);
          wr0 = gw[0]; wr1 = gw[1]; wr2 = gw[2]; wr3 = gw[3];
        } else {
          const uint4* gw = reinterpret_cast<const uint4*>(
              (const u16*)W + (size_t)(oo0 + wrow) * 512 + k0 + wcol);
          wr0 = gw[0]; wr1 = gw[1];
        }
      }
    }

    // ks = 1 half
    {
      bf16x8 av0 = *reinterpret_cast<const bf16x8*>(&As[bf][w * 32 + c][32 + quad * 8]);
      bf16x8 av1 = *reinterpret_cast<const bf16x8*>(&As[bf][w * 32 + 16 + c][32 + quad * 8]);
#pragma unroll
      for (int ot = 0; ot < 4; ++ot) {
        bf16x8 wv = *reinterpret_cast<const bf16x8*>(&Ws[bf][ot * 16 + c][32 + quad * 8]);
        if (MODE == 3) {
          acc[0][ot] = __builtin_amdgcn_mfma_f32_16x16x32_bf16(wv, av0, acc[0][ot], 0, 0, 0);
          acc[1][ot] = __builtin_amdgcn_mfma_f32_16x16x32_bf16(wv, av1, acc[1][ot], 0, 0, 0);
        } else {
          acc[0][ot] = __builtin_amdgcn_mfma_f32_16x16x32_bf16(av0, wv, acc[0][ot], 0, 0, 0);
          acc[1][ot] = __builtin_amdgcn_mfma_f32_16x16x32_bf16(av1, wv, acc[1][ot], 0, 0, 0);
        }
      }
    }
  }

  if (MODE == 0) {
    const int h = oo0 >> 6, bh = b * 8 + h;
#pragma unroll
    for (int ot = 0; ot < 4; ++ot) {
      int o = oo0 + ot * 16 + c;
      int d = o & 63;
      float bv = ldf(bias, o, f32);
      float qs = 0.f;
#pragma unroll
      for (int nt = 0; nt < 2; ++nt)
#pragma unroll
        for (int r = 0; r < 4; ++r) {
          int m = m0 + w * 32 + nt * 16 + quad * 4 + r;
          float qv = acc[nt][ot][r] + bv;
          o0[((size_t)bh * M + m) * 64 + d] = f2bs(qv * 0.125f);
          qs += qv;
        }
      qs += __shfl_xor(qs, 16, 64);
      qs += __shfl_xor(qs, 32, 64);
      if (quad == 0) atomicAdd(&qsum[bh * 64 + d], qs);
    }
  } else {
#pragma unroll
    for (int ot = 0; ot < 4; ++ot)
#pragma unroll
      for (int r = 0; r < 4; ++r) {
        int o = oo0 + ot * 16 + quad * 4 + r;
        float bv = ldf(bias, o, f32);
#pragma unroll
        for (int nt = 0; nt < 2; ++nt) {
          int m = m0 + w * 32 + nt * 16 + c;
          float val = acc[nt][ot][r] + bv;
          size_t oi_ = ((size_t)(b * 512 + o)) * M + m;
          if (f32) ((float*)ob)[oi_] = val;
          else     ((u16*)ob)[oi_] = f2bs(val);
        }
      }
  }
}

// ---------------------------------------------------------------------------
// 64x64 MFMA conv1x1 GEMM for kv_up (r13-proven dbuf + named-scalar prefetch,
// 1 barrier/K-step). kb [bh][m][64], v2 swizzled.
// v2 index for V[d][m] (per bh): ((ch*2+s)*4+dt)*512 + (q2*16+cc)*8 + e
// ---------------------------------------------------------------------------
__global__ __launch_bounds__(256) void gemm_kv(
    const u16* __restrict__ A, const void* __restrict__ W,
    const void* __restrict__ bias, u16* __restrict__ kb, u16* __restrict__ v2,
    int M, const int* __restrict__ dtf) {
  const int f32 = *dtf;
  const int b = blockIdx.z, m0 = blockIdx.x * 64, oo0 = blockIdx.y * 64;
  const int t = threadIdx.x, w = t >> 6, lane = t & 63;
  const int quad = lane >> 4, c = lane & 15;
  __shared__ __align__(16) u16 As[2][64][72];
  __shared__ __align__(16) u16 Ws[2][64][72];
  f32x4 acc[4];
#pragma unroll
  for (int ot = 0; ot < 4; ++ot) acc[ot] = (f32x4){0.f, 0.f, 0.f, 0.f};
  const u16* Ab = A + (size_t)b * M * 512;
  const int srow = t >> 2, scol = (t & 3) * 16;

  uint4 ar0, ar1, wr0, wr1, wr2, wr3;

  {
    const uint4* gs = reinterpret_cast<const uint4*>(Ab + (size_t)(m0 + srow) * 512 + scol);
    *reinterpret_cast<uint4*>(&As[0][srow][scol])     = gs[0];
    *reinterpret_cast<uint4*>(&As[0][srow][scol + 8]) = gs[1];
    if (f32) {
      const float* gw = (const float*)W + (size_t)(oo0 + srow) * 512 + scol;
#pragma unroll
      for (int e = 0; e < 16; ++e) Ws[0][srow][scol + e] = f2bs(gw[e]);
    } else {
      const u16* gw = (const u16*)W + (size_t)(oo0 + srow) * 512 + scol;
      *reinterpret_cast<uint4*>(&Ws[0][srow][scol])     = *reinterpret_cast<const uint4*>(gw);
      *reinterpret_cast<uint4*>(&Ws[0][srow][scol + 8]) = *reinterpret_cast<const uint4*>(gw + 8);
    }
    const uint4* gs1 = reinterpret_cast<const uint4*>(Ab + (size_t)(m0 + srow) * 512 + 64 + scol);
    ar0 = gs1[0]; ar1 = gs1[1];
    if (f32) {
      const uint4* gw = reinterpret_cast<const uint4*>(
          (const float*)W + (size_t)(oo0 + srow) * 512 + 64 + scol);
      wr0 = gw[0]; wr1 = gw[1]; wr2 = gw[2]; wr3 = gw[3];
    } else {
      const uint4* gw = reinterpret_cast<const uint4*>(
          (const u16*)W + (size_t)(oo0 + srow) * 512 + 64 + scol);
      wr0 = gw[0]; wr1 = gw[1];
    }
  }

  for (int ki = 0; ki < 8; ++ki) {
    __syncthreads();
    const int bf = ki & 1;

    {
      bf16x8 av = *reinterpret_cast<const bf16x8*>(&As[bf][w * 16 + c][quad * 8]);
#pragma unroll
      for (int ot = 0; ot < 4; ++ot) {
        bf16x8 wv = *reinterpret_cast<const bf16x8*>(&Ws[bf][ot * 16 + c][quad * 8]);
        acc[ot] = __builtin_amdgcn_mfma_f32_16x16x32_bf16(av, wv, acc[ot], 0, 0, 0);
      }
    }

    if (ki + 1 < 8) {
      *reinterpret_cast<uint4*>(&As[bf ^ 1][srow][scol])     = ar0;
      *reinterpret_cast<uint4*>(&As[bf ^ 1][srow][scol + 8]) = ar1;
      if (f32) {
        float tf[16];
        __builtin_memcpy(&tf[0],  &wr0, 16);
        __builtin_memcpy(&tf[4],  &wr1, 16);
        __builtin_memcpy(&tf[8],  &wr2, 16);
        __builtin_memcpy(&tf[12], &wr3, 16);
#pragma unroll
        for (int e = 0; e < 16; ++e) Ws[bf ^ 1][srow][scol + e] = f2bs(tf[e]);
      } else {
        *reinterpret_cast<uint4*>(&Ws[bf ^ 1][srow][scol])     = wr0;
        *reinterpret_cast<uint4*>(&Ws[bf ^ 1][srow][scol + 8]) = wr1;
      }
      if (ki + 2 < 8) {
        const int k0 = (ki + 2) * 64;
        const uint4* gs = reinterpret_cast<const uint4*>(Ab + (size_t)(m0 + srow) * 512 + k0 + scol);
        ar0 = gs[0]; ar1 = gs[1];
        if (f32) {
          const uint4* gw = reinterpret_cast<const uint4*>(
              (const float*)W + (size_t)(oo0 + srow) * 512 + k0 + scol);
          wr0 = gw[0]; wr1 = gw[1]; wr2 = gw[2]; wr3 = gw[3];
        } else {
          const uint4* gw = reinterpret_cast<const uint4*>(
              (const u16*)W + (size_t)(oo0 + srow) * 512 + k0 + scol);
          wr0 = gw[0]; wr1 = gw[1];
        }
      }
    }

    {
      bf16x8 av = *reinterpret_cast<const bf16x8*>(&As[bf][w * 16 + c][32 + quad * 8]);
#pragma unroll
      for (int ot = 0; ot < 4; ++ot) {
        bf16x8 wv = *reinterpret_cast<const bf16x8*>(&Ws[bf][ot * 16 + c][32 + quad * 8]);
        acc[ot] = __builtin_amdgcn_mfma_f32_16x16x32_bf16(av, wv, acc[ot], 0, 0, 0);
      }
    }
  }

#pragma unroll
  for (int ot = 0; ot < 4; ++ot) {
    int o = oo0 + ot * 16 + c;
    float bv = ldf(bias, o, f32);
    int hh = o >> 7, jj = o & 127;
#pragma unroll
    for (int r = 0; r < 4; ++r) {
      int m = m0 + w * 16 + quad * 4 + r;
      u16 val = f2bs(acc[ot][r] + bv);
      if (jj < 64) {
        kb[((size_t)(b * 8 + hh) * M + m) * 64 + jj] = val;
      } else {
        int d = jj & 63;
        v2[((((size_t)(b * 8 + hh) * 16 + (m >> 6)) * 2 + ((m >> 5) & 1)) * 4 + (d >> 4)) * 512
           + (((m >> 3) & 3) * 16 + (d & 15)) * 8 + (m & 7)] = val;
      }
    }
  }
}

// ---------------------------------------------------------------------------
// scores -> top-16 coarse cells -> 64 full-res positions into posb.
// Vectorized score loads (8 x uint4/row); per-wave shfl_xor selection.
// ---------------------------------------------------------------------------
__global__ __launch_bounds__(256) void topk_kernel(
    const float* __restrict__ qsum, const u16* __restrict__ k,
    const float* __restrict__ heat, const void* __restrict__ gumbel,
    int* __restrict__ posb, const int* __restrict__ dtf) {
  const int f32 = *dtf;
  int bh = blockIdx.x, b = bh >> 3, t = threadIdx.x;
  const int lane = t & 63, w = t >> 6;
  __shared__ float qs[64];
  __shared__ float s[1024];
  __shared__ float rv[4];
  __shared__ int   ri[4];
  if (t < 64) qs[t] = qsum[bh * 64 + t];
  __syncthreads();
  for (int j = 0; j < 4; ++j) {
    int m = t + j * 256;
    const uint4* kr = reinterpret_cast<const uint4*>(k + ((size_t)bh * 1024 + m) * 64);
    float dot = 0.f;
#pragma unroll
    for (int v = 0; v < 8; ++v) {
      uint4 kq = kr[v];
      u16 tmp[8];
      *reinterpret_cast<uint4*>(tmp) = kq;
#pragma unroll
      for (int e = 0; e < 8; ++e) dot += qs[v * 8 + e] * bs2f(tmp[e]);
    }
    s[m] = dot * (0.125f / 4096.0f) * (heat[b * 1024 + m] * (1.0f / 2048.0f)) +
           ldf(gumbel, (size_t)bh * 1024 + m, f32);
  }
  __syncthreads();
  for (int it = 0; it < 16; ++it) {
    float bv = -1e30f; int bi = 0x7fffffff;
    for (int j = 0; j < 4; ++j) {
      int m = t + j * 256; float vv = s[m];
      if (vv > bv || (vv == bv && m < bi)) { bv = vv; bi = m; }
    }
#pragma unroll
    for (int off = 1; off < 64; off <<= 1) {
      float ov = __shfl_xor(bv, off, 64);
      int   oi = __shfl_xor(bi, off, 64);
      if (ov > bv || (ov == bv && oi < bi)) { bv = ov; bi = oi; }
    }
    if (lane == 0) { rv[w] = bv; ri[w] = bi; }
    __syncthreads();
    if (t == 0) {
      float fv = rv[0]; int fi = ri[0];
#pragma unroll
      for (int ww = 1; ww < 4; ++ww)
        if (rv[ww] > fv || (rv[ww] == fv && ri[ww] < fi)) { fv = rv[ww]; fi = ri[ww]; }
      s[fi] = -1e30f;
      int hy = (fi >> 5) * 2, wx = (fi & 31) * 2;
      posb[bh * 64 + it]      = hy * 64 + wx;
      posb[bh * 64 + 16 + it] = hy * 64 + wx + 1;
      posb[bh * 64 + 32 + it] = (hy + 1) * 64 + wx;
      posb[bh * 64 + 48 + it] = (hy + 1) * 64 + wx + 1;
    }
    __syncthreads();
  }
}

// ---------------------------------------------------------------------------
// gather_kv as MFMA GEMM (r14-proven named-scalar dbuf, 1 barrier/K-step).
// ---------------------------------------------------------------------------
__global__ __launch_bounds__(256) void gather_kv_mfma(
    const u16* __restrict__ xT, const void* __restrict__ kv_w,
    const void* __restrict__ kv_b, const int* __restrict__ posb,
    u16* __restrict__ tkb, u16* __restrict__ tvTb,
    const int* __restrict__ dtf) {
  const int f32 = *dtf;
  const int bh = blockIdx.x, b = bh >> 3, h = bh & 7;
  const int half = blockIdx.y;
  const int t = threadIdx.x, w = t >> 6, lane = t & 63;
  const int quad = lane >> 4, c = lane & 15;
  __shared__ int pos[64];
  __shared__ __align__(16) u16 As[2][64][72];
  __shared__ __align__(16) u16 Ws[2][64][72];
  if (t < 64) pos[t] = posb[bh * 64 + t];
  __syncthreads();
  const int obase = h * 128 + half * 64;
  const int srow = t >> 2, scol = (t & 3) * 16;
  const int arow = pos[srow];
  const u16* Ab = xT + ((size_t)b * 4096 + arow) * 512;
  f32x4 acc[4];
#pragma unroll
  for (int ot = 0; ot < 4; ++ot) acc[ot] = (f32x4){0.f, 0.f, 0.f, 0.f};

  uint4 ar0, ar1, wr0, wr1, wr2, wr3;

  {
    const uint4* gs = reinterpret_cast<const uint4*>(Ab + scol);
    *reinterpret_cast<uint4*>(&As[0][srow][scol])     = gs[0];
    *reinterpret_cast<uint4*>(&As[0][srow][scol + 8]) = gs[1];
    if (f32) {
      const float* gw = (const float*)kv_w + (size_t)(obase + srow) * 512 + scol;
#pragma unroll
      for (int e = 0; e < 16; ++e) Ws[0][srow][scol + e] = f2bs(gw[e]);
    } else {
      const u16* gw = (const u16*)kv_w + (size_t)(obase + srow) * 512 + scol;
      *reinterpret_cast<uint4*>(&Ws[0][srow][scol])     = *reinterpret_cast<const uint4*>(gw);
      *reinterpret_cast<uint4*>(&Ws[0][srow][scol + 8]) = *reinterpret_cast<const uint4*>(gw + 8);
    }
    const uint4* gs1 = reinterpret_cast<const uint4*>(Ab + 64 + scol);
    ar0 = gs1[0]; ar1 = gs1[1];
    if (f32) {
      const uint4* gw = reinterpret_cast<const uint4*>(
          (const float*)kv_w + (size_t)(obase + srow) * 512 + 64 + scol);
      wr0 = gw[0]; wr1 = gw[1]; wr2 = gw[2]; wr3 = gw[3];
    } else {
      const uint4* gw = reinterpret_cast<const uint4*>(
          (const u16*)kv_w + (size_t)(obase + srow) * 512 + 64 + scol);
      wr0 = gw[0]; wr1 = gw[1];
    }
  }

  for (int ki = 0; ki < 8; ++ki) {
    __syncthreads();
    const int bf = ki & 1;

    {
      bf16x8 av = *reinterpret_cast<const bf16x8*>(&As[bf][w * 16 + c][quad * 8]);
#pragma unroll
      for (int ot = 0; ot < 4; ++ot) {
        bf16x8 wv = *reinterpret_cast<const bf16x8*>(&Ws[bf][ot * 16 + c][quad * 8]);
        acc[ot] = __builtin_amdgcn_mfma_f32_16x16x32_bf16(av, wv, acc[ot], 0, 0, 0);
      }
    }

    if (ki + 1 < 8) {
      *reinterpret_cast<uint4*>(&As[bf ^ 1][srow][scol])     = ar0;
      *reinterpret_cast<uint4*>(&As[bf ^ 1][srow][scol + 8]) = ar1;
      if (f32) {
        float tf[16];
        __builtin_memcpy(&tf[0],  &wr0, 16);
        __builtin_memcpy(&tf[4],  &wr1, 16);
        __builtin_memcpy(&tf[8],  &wr2, 16);
        __builtin_memcpy(&tf[12], &wr3, 16);
#pragma unroll
        for (int e = 0; e < 16; ++e) Ws[bf ^ 1][srow][scol + e] = f2bs(tf[e]);
      } else {
        *reinterpret_cast<uint4*>(&Ws[bf ^ 1][srow][scol])     = wr0;
        *reinterpret_cast<uint4*>(&Ws[bf ^ 1][srow][scol + 8]) = wr1;
      }
      if (ki + 2 < 8) {
        const int k0 = (ki + 2) * 64;
        const uint4* gs = reinterpret_cast<const uint4*>(Ab + k0 + scol);
        ar0 = gs[0]; ar1 = gs[1];
        if (f32) {
          const uint4* gw = reinterpret_cast<const uint4*>(
              (const float*)kv_w + (size_t)(obase + srow) * 512 + k0 + scol);
          wr0 = gw[0]; wr1 = gw[1]; wr2 = gw[2]; wr3 = gw[3];
        } else {
          const uint4* gw = reinterpret_cast<const uint4*>(
              (const u16*)kv_w + (size_t)(obase + srow) * 512 + k0 + scol);
          wr0 = gw[0]; wr1 = gw[1];
        }
      }
    }

    {
      bf16x8 av = *reinterpret_cast<const bf16x8*>(&As[bf][w * 16 + c][32 + quad * 8]);
#pragma unroll
      for (int ot = 0; ot < 4; ++ot) {
        bf16x8 wv = *reinterpret_cast<const bf16x8*>(&Ws[bf][ot * 16 + c][32 + quad * 8]);
        acc[ot] = __builtin_amdgcn_mfma_f32_16x16x32_bf16(av, wv, acc[ot], 0, 0, 0);
      }
    }
  }

#pragma unroll
  for (int ot = 0; ot < 4; ++ot) {
    int d = ot * 16 + c;
    float bv = ldf(kv_b, obase + d, f32);
#pragma unroll
    for (int r = 0; r < 4; ++r) {
      int m = w * 16 + quad * 4 + r;
      u16 val = f2bs(acc[ot][r] + bv);
      if (half) tvTb[((size_t)bh * 64 + d) * 64 + m] = val;
      else      tkb[((size_t)bh * 64 + m) * 64 + d] = val;
    }
  }
}

// ---------------------------------------------------------------------------
// depthwise 7x7 conv on v (v2 swizzled layout) -> vpe bf16 (strip structure:
// 4-row column strip per thread, weights in regs, row segments reused across
// output rows; DS reads/thread 392 -> ~119).
// ---------------------------------------------------------------------------
__global__ __launch_bounds__(256) void dwconv_kernel(
    const u16* __restrict__ v2, const void* __restrict__ pe_w,
    const void* __restrict__ pe_b, u16* __restrict__ vpe,
    const int* __restrict__ dtf) {
  const int f32 = *dtf;
  int bc = blockIdx.x;
  int b = bc >> 9, c = bc & 511;
  int h = c >> 6, d = c & 63;
  int dt = d >> 4, cc = d & 15;
  int t = threadIdx.x;
  __shared__ float img[1024];
  __shared__ float wts[49];
  if (t < 128) {
    int ch = t >> 3, s = (t >> 2) & 1, q2 = t & 3;
    const u16* src = v2 + ((((size_t)(b * 8 + h) * 16 + ch) * 2 + s) * 4 + dt) * 512
                        + (q2 * 16 + cc) * 8;
    uint4 v4 = *reinterpret_cast<const uint4*>(src);
    u16 tmp[8];
    *reinterpret_cast<uint4*>(tmp) = v4;
#pragma unroll
    for (int e = 0; e < 8; ++e) img[t * 8 + e] = bs2f(tmp[e]);
  }
  if (t < 49) wts[t] = ldf(pe_w, c * 49 + t, f32);
  float bias = ldf(pe_b, c, f32);
  __syncthreads();

  float wreg[49];
#pragma unroll
  for (int i = 0; i < 49; ++i) wreg[i] = wts[i];

  const int x = t & 31, y0 = (t >> 5) * 4;
  float acc[4] = {0.f, 0.f, 0.f, 0.f};
#pragma unroll
  for (int r = 0; r < 10; ++r) {
    int yy = y0 - 3 + r;
    if ((unsigned)yy >= 32u) continue;
    float rr[7];
#pragma unroll
    for (int j = 0; j < 7; ++j) {
      int xc = x - 3 + j;
      rr[j] = ((unsigned)xc < 32u) ? img[yy * 32 + xc] : 0.f;
    }
#pragma unroll
    for (int p = 0; p < 4; ++p) {
      int ky = r - p;                 // yy = (y0+p) + ky - 3
      if (ky < 0 || ky > 6) continue;
      float s2 = 0.f;
#pragma unroll
      for (int j = 0; j < 7; ++j) s2 += rr[j] * wreg[ky * 7 + j];
      acc[p] += s2;
    }
  }
#pragma unroll
  for (int p = 0; p < 4; ++p)
    vpe[(size_t)bc * 1024 + (y0 + p) * 32 + x] = f2bs(acc[p] + bias);
}

// ---------------------------------------------------------------------------
// FUSED coarse+fine attention (r6/r10 structure — proven 47us local optimum).
// 64-row blocks (grid 64 x 16bh, 4 blocks/CU, 16 waves/CU); K LDS-dbuf with
// register prefetch (1 barrier/chunk); V register-direct from v2 (coalesced,
// in-chunk issue distance). UNCHANGED.
// ---------------------------------------------------------------------------
__global__ __launch_bounds__(256, 4) void attn_fused(
    const u16* __restrict__ q, const u16* __restrict__ k,
    const u16* __restrict__ v2, const u16* __restrict__ tkb,
    const u16* __restrict__ tvTb, const u16* __restrict__ gwb,
    const float* __restrict__ gbf, const u16* __restrict__ vpe,
    u16* __restrict__ xsT) {
  const int bh = blockIdx.y, b = bh >> 3, h = bh & 7;
  const int bx = blockIdx.x;          // output image row y = bx
  const int n0 = bx * 64;
  const int t = threadIdx.x, w = t >> 6, lane = t & 63;
  const int quad = lane >> 4, c = lane & 15;

  __shared__ __align__(16) u16 lds[13824];   // 27.6 KB union
  u16* Ks = lds;              // [2][64][72] K double-buffer
  u16* Ps = lds + 9216;       // [4][16][72] per-wave P tiles

  // ---- phase A: coarse ----
  bf16x8 bq[2];
  {
    const u16* qr = q + ((size_t)bh * 4096 + n0 + w * 16 + c) * 64;
    bq[0] = *reinterpret_cast<const bf16x8*>(qr + quad * 8);
    bq[1] = *reinterpret_cast<const bf16x8*>(qr + 32 + quad * 8);
  }
  f32x4 po[4];
#pragma unroll
  for (int dt = 0; dt < 4; ++dt) po[dt] = (f32x4){0.f, 0.f, 0.f, 0.f};
  float sume = 0.f;

  const u16* kbase = k + (size_t)bh * 65536;
  const u16* v2base = v2 + (size_t)bh * 65536;
  const int srow = t >> 2, scol = (t & 3) * 16;

  uint4 kr0, kr1;
  {
    // chunk 0 staged directly into buf 0
    const u16* gk = kbase + (size_t)srow * 64 + scol;
    kr0 = *reinterpret_cast<const uint4*>(gk);
    kr1 = *reinterpret_cast<const uint4*>(gk + 8);
    *reinterpret_cast<uint4*>(&Ks[srow * 72 + scol])     = kr0;
    *reinterpret_cast<uint4*>(&Ks[srow * 72 + scol + 8]) = kr1;
    // prefetch chunk 1 into regs
    const u16* gk1 = kbase + (size_t)(64 + srow) * 64 + scol;
    kr0 = *reinterpret_cast<const uint4*>(gk1);
    kr1 = *reinterpret_cast<const uint4*>(gk1 + 8);
  }

  for (int ch = 0; ch < 16; ++ch) {
    __syncthreads();
    const int buf = ch & 1;

    // V fragments: coalesced register-direct loads (consumed at PV)
    bf16x8 av[4][2];
    {
      const u16* v2c = v2base + (size_t)ch * 4096;
#pragma unroll
      for (int dt = 0; dt < 4; ++dt) {
        av[dt][0] = *reinterpret_cast<const bf16x8*>(v2c + dt * 512 + lane * 8);
        av[dt][1] = *reinterpret_cast<const bf16x8*>(v2c + 2048 + dt * 512 + lane * 8);
      }
    }

    // QK from LDS K buffer
    f32x4 st[4];
#pragma unroll
    for (int mt = 0; mt < 4; ++mt) {
      const u16* krow = &Ks[buf * 4608 + (mt * 16 + c) * 72];
      bf16x8 ak0 = *reinterpret_cast<const bf16x8*>(krow + quad * 8);
      bf16x8 ak1 = *reinterpret_cast<const bf16x8*>(krow + 32 + quad * 8);
      f32x4 acc = (f32x4){0.f, 0.f, 0.f, 0.f};
      acc = __builtin_amdgcn_mfma_f32_16x16x32_bf16(ak0, bq[0], acc, 0, 0, 0);
      acc = __builtin_amdgcn_mfma_f32_16x16x32_bf16(ak1, bq[1], acc, 0, 0, 0);
      st[mt] = acc;
    }

    // stage prefetched K into other buffer; prefetch ch+2
    if (ch + 1 < 16) {
      *reinterpret_cast<uint4*>(&Ks[(buf ^ 1) * 4608 + srow * 72 + scol])     = kr0;
      *reinterpret_cast<uint4*>(&Ks[(buf ^ 1) * 4608 + srow * 72 + scol + 8]) = kr1;
      if (ch + 2 < 16) {
        const u16* gk = kbase + (size_t)((ch + 2) * 64 + srow) * 64 + scol;
        kr0 = *reinterpret_cast<const uint4*>(gk);
        kr1 = *reinterpret_cast<const uint4*>(gk + 8);
      }
    }

    // softmax numerator (q pre-scaled; raw exp)
    float cs = 0.f;
    u16* psw = &Ps[(w * 16 + c) * 72];
#pragma unroll
    for (int mt = 0; mt < 4; ++mt) {
      float e0 = __expf(st[mt][0]);
      float e1 = __expf(st[mt][1]);
      float e2 = __expf(st[mt][2]);
      float e3 = __expf(st[mt][3]);
      cs += (e0 + e1) + (e2 + e3);
      ushort4 pw;
      pw.x = f2bs(e0); pw.y = f2bs(e1); pw.z = f2bs(e2); pw.w = f2bs(e3);
      *reinterpret_cast<ushort4*>(psw + mt * 16 + quad * 4) = pw;
    }
    cs += __shfl_xor(cs, 16, 64);
    cs += __shfl_xor(cs, 32, 64);
    sume += cs;

    // PV
#pragma unroll
    for (int s = 0; s < 2; ++s) {
      bf16x8 bp = *reinterpret_cast<const bf16x8*>(psw + s * 32 + quad * 8);
#pragma unroll
      for (int dt = 0; dt < 4; ++dt) {
        po[dt] = __builtin_amdgcn_mfma_f32_16x16x32_bf16(av[dt][s], bp, po[dt], 0, 0, 0);
      }
    }
  }

  __syncthreads();  // phase A LDS dead; repartition
  u16* fus = lds;                       // [4][16][136]
  u16* vl  = lds + 8704;                // [2][64][36]
  float* gbl = (float*)(lds + 13312);   // [64]

  // block-uniform bilinear y setup (all rows of this block have y = bx)
  const int ym = bx >> 1;
  int r0_, r1_; float wy0, wy1;
  if ((bx & 1) == 0) { r0_ = ym > 0 ? ym - 1 : 0; r1_ = ym; wy0 = 0.25f; wy1 = 0.75f; }
  else               { r0_ = ym; r1_ = ym < 31 ? ym + 1 : 31; wy0 = 0.75f; wy1 = 0.25f; }

  for (int idx = t; idx < 512; idx += 256) {
    int seg = idx & 3, ch2 = (idx >> 2) & 63, rr = idx >> 8;
    int vrow = rr ? r1_ : r0_;
    const uint4 v4 = *reinterpret_cast<const uint4*>(
        vpe + ((size_t)(b * 512 + h * 64 + ch2)) * 1024 + vrow * 32 + seg * 8);
    u16* dst = &vl[(rr * 64 + ch2) * 36 + seg * 8];
    uint2 lo, hi;
    lo.x = v4.x; lo.y = v4.y; hi.x = v4.z; hi.y = v4.w;
    *reinterpret_cast<uint2*>(dst)     = lo;
    *reinterpret_cast<uint2*>(dst + 4) = hi;
  }
  if (t < 64) gbl[t] = gbf[t];
  __syncthreads();

  // ---- phase B: fine, per wave (16 q-rows each) ----
  u16* fusw = &fus[(w * 16 + c) * 136];
  f32x4 st2[4];
#pragma unroll
  for (int mt = 0; mt < 4; ++mt) {
    f32x4 acc = (f32x4){0.f, 0.f, 0.f, 0.f};
#pragma unroll
    for (int s = 0; s < 2; ++s) {
      bf16x8 ak = *reinterpret_cast<const bf16x8*>(
          &tkb[((size_t)bh * 64 + mt * 16 + c) * 64 + s * 32 + quad * 8]);
      acc = __builtin_amdgcn_mfma_f32_16x16x32_bf16(ak, bq[s], acc, 0, 0, 0);
    }
    st2[mt] = acc;
  }
  float sume2 = 0.f;
#pragma unroll
  for (int mt = 0; mt < 4; ++mt) {
    float e0 = __expf(st2[mt][0]);
    float e1 = __expf(st2[mt][1]);
    float e2 = __expf(st2[mt][2]);
    float e3 = __expf(st2[mt][3]);
    sume2 += (e0 + e1) + (e2 + e3);
    ushort4 pw;
    pw.x = f2bs(e0); pw.y = f2bs(e1); pw.z = f2bs(e2); pw.w = f2bs(e3);
    *reinterpret_cast<ushort4*>(fusw + mt * 16 + quad * 4) = pw;
  }
  sume2 += __shfl_xor(sume2, 16, 64);
  sume2 += __shfl_xor(sume2, 32, 64);
  float inv2 = 1.0f / sume2;

  f32x4 po2[4];
#pragma unroll
  for (int dt = 0; dt < 4; ++dt) po2[dt] = (f32x4){0.f, 0.f, 0.f, 0.f};
#pragma unroll
  for (int s = 0; s < 2; ++s) {
    bf16x8 bp = *reinterpret_cast<const bf16x8*>(fusw + s * 32 + quad * 8);
#pragma unroll
    for (int dt = 0; dt < 4; ++dt) {
      bf16x8 av = *reinterpret_cast<const bf16x8*>(
          &tvTb[((size_t)bh * 64 + dt * 16 + c) * 64 + s * 32 + quad * 8]);
      po2[dt] = __builtin_amdgcn_mfma_f32_16x16x32_bf16(av, bp, po2[dt], 0, 0, 0);
    }
  }

  // fusion [coarse | refined]
  float invc = 1.0f / sume;
#pragma unroll
  for (int dt = 0; dt < 4; ++dt) {
    ushort4 cw, rw;
    cw.x = f2bs(po[dt][0] * invc); cw.y = f2bs(po[dt][1] * invc);
    cw.z = f2bs(po[dt][2] * invc); cw.w = f2bs(po[dt][3] * invc);
    rw.x = f2bs(po2[dt][0] * inv2); rw.y = f2bs(po2[dt][1] * inv2);
    rw.z = f2bs(po2[dt][2] * inv2); rw.w = f2bs(po2[dt][3] * inv2);
    *reinterpret_cast<ushort4*>(fusw + dt * 16 + quad * 4)      = cw;
    *reinterpret_cast<ushort4*>(fusw + 64 + dt * 16 + quad * 4) = rw;
  }

  // gate MFMA (K=128), A-frags from global gwb
  f32x4 ga[4];
#pragma unroll
  for (int ot = 0; ot < 4; ++ot) ga[ot] = (f32x4){0.f, 0.f, 0.f, 0.f};
#pragma unroll
  for (int s = 0; s < 4; ++s) {
    bf16x8 bf = *reinterpret_cast<const bf16x8*>(fusw + s * 32 + quad * 8);
#pragma unroll
    for (int ot = 0; ot < 4; ++ot) {
      bf16x8 ag = *reinterpret_cast<const bf16x8*>(
          gwb + (ot * 16 + c) * 128 + s * 32 + quad * 8);
      ga[ot] = __builtin_amdgcn_mfma_f32_16x16x32_bf16(ag, bf, ga[ot], 0, 0, 0);
    }
  }

  // combine + bilinear; overwrite fus rows 0..63 (same-lane read->write)
  const int x = w * 16 + c;              // x coordinate of this q-row
  int jx = x >> 1, x0, x1; float wx0, wx1;
  if ((x & 1) == 0) { x0 = (jx > 0) ? jx - 1 : 0; x1 = jx; wx0 = 0.25f; wx1 = 0.75f; }
  else              { x0 = jx; x1 = (jx < 31) ? jx + 1 : 31; wx0 = 0.75f; wx1 = 0.25f; }
#pragma unroll
  for (int dt = 0; dt < 4; ++dt) {
    ushort4 ow;
    u16 tmp[4];
#pragma unroll
    for (int r = 0; r < 4; ++r) {
      int row = dt * 16 + quad * 4 + r;
      float ref = po2[dt][r] * inv2;
      float coar = bs2f(fusw[row]);
      float g = 1.0f / (1.0f + __expf(-(ga[dt][r] + gbl[row])));
      float vv = wy0 * (wx0 * bs2f(vl[row * 36 + x0]) +
                        wx1 * bs2f(vl[row * 36 + x1])) +
                 wy1 * (wx0 * bs2f(vl[(64 + row) * 36 + x0]) +
                        wx1 * bs2f(vl[(64 + row) * 36 + x1]));
      tmp[r] = f2bs(g * ref + (1.0f - g) * coar + vv);
    }
    ow.x = tmp[0]; ow.y = tmp[1]; ow.z = tmp[2]; ow.w = tmp[3];
    *reinterpret_cast<ushort4*>(fusw + dt * 16 + quad * 4) = ow;
  }

  // store n-major rows (same-wave cross-lane reads, in-order DS)
  {
    int nl = lane >> 2, cs2 = (lane & 3) * 16;
    const u16* srcrow = &fus[(w * 16 + nl) * 136 + cs2];
    u16* dst = xsT + ((size_t)b * 4096 + n0 + w * 16 + nl) * 512 + h * 64 + cs2;
    *reinterpret_cast<uint4*>(dst)     = *reinterpret_cast<const uint4*>(srcrow);
    *reinterpret_cast<uint4*>(dst + 8) = *reinterpret_cast<const uint4*>(srcrow + 8);
  }
}

extern "C" void kernel_launch(void* const* d_in, const int* in_sizes, int n_in,
                              void* d_out, int out_size, void* d_ws, size_t ws_size,
                              hipStream_t stream) {
  const void* x    = d_in[0];
  const void* up   = d_in[1];
  const void* gum  = d_in[2];
  const void* q_w  = d_in[3];
  const void* q_b  = d_in[4];
  const void* kv_w = d_in[5];
  const void* kv_b = d_in[6];
  const void* p_w  = d_in[7];
  const void* p_b  = d_in[8];
  const void* pe_w = d_in[9];
  const void* pe_b = d_in[10];
  const void* g_w  = d_in[11];
  const void* g_b  = d_in[12];

  float* ws    = (float*)d_ws;
  int*   dtf   = (int*)ws;                   // 16 f
  float* qsum  = ws + 16;                    // 1024 f
  float* heat  = qsum + 1024;                // 2048 f
  int*   posb  = (int*)(heat + 2048);        // 1024 ints
  float* gbf   = (float*)(posb + 1024);      // 64
  u16*   gwb   = (u16*)(gbf + 64);           // 8192 u16
  u16*   tkb   = gwb + 8192;                 // 65536
  u16*   tvTb  = tkb + 65536;                // 65536
  u16*   qb    = tvTb + 65536;               // 4M
  u16*   kb    = qb + 4194304;               // 1M
  u16*   v2b   = kb + 1048576;               // 1M   (swizzled V)
  u16*   xT    = v2b + 1048576;              // 4M
  u16*   upT   = xT + 4194304;               // 1M
  u16*   xsT   = upT + 1048576;              // 4M
  u16*   vpe   = xsT + 4194304;              // 1M   (~26 MB total)

  dim3 blk(256);
  hipMemsetAsync(ws, 0, (16 + 1024 + 2048) * 4, stream);
  detect_dtype<<<dim3(64), blk, 0, stream>>>((const uint4*)x, dtf);
  prep_gate<<<dim3(1), blk, 0, stream>>>(g_w, g_b, gwb, gbf, dtf);
  transpose_bf16<<<dim3(64, 8, 2), blk, 0, stream>>>(x, xT, 4096, heat, dtf);
  transpose_bf16<<<dim3(16, 8, 2), blk, 0, stream>>>(up, upT, 1024, nullptr, dtf);
  gemm128<0><<<dim3(32, 8, 2), blk, 0, stream>>>(xT, q_w, q_b, qb, nullptr, qsum, 4096, dtf);
  gemm_kv<<<dim3(16, 16, 2), blk, 0, stream>>>(upT, kv_w, kv_b, kb, v2b, 1024, dtf);
  topk_kernel<<<dim3(16), blk, 0, stream>>>(qsum, kb, heat, gum, posb, dtf);
  gather_kv_mfma<<<dim3(16, 2), blk, 0, stream>>>(xT, kv_w, kv_b, posb, tkb, tvTb, dtf);
  dwconv_kernel<<<dim3(1024), blk, 0, stream>>>(v2b, pe_w, pe_b, vpe, dtf);
  attn_fused<<<dim3(64, 16), blk, 0, stream>>>(qb, kb, v2b, tkb, tvTb, gwb, gbf, vpe, xsT);
  gemm128<3><<<dim3(32, 8, 2), blk, 0, stream>>>(xsT, p_w, p_b, nullptr, d_out, nullptr, 4096, dtf);
}

// Round 17
// 234.677 us; speedup vs baseline: 1.0241x; 1.0046x over previous
//
#include <hip/hip_runtime.h>
#include <hip/hip_bf16.h>
#include <cstdint>

typedef __hip_bfloat16 bf16;
typedef unsigned short u16;
typedef __attribute__((ext_vector_type(8))) short bf16x8;
typedef __attribute__((ext_vector_type(4))) float f32x4;

static __device__ __forceinline__ float bs2f(u16 s) {
  unsigned int u = ((unsigned int)s) << 16;
  float f;
  __builtin_memcpy(&f, &u, 4);
  return f;
}
static __device__ __forceinline__ u16 f2bs(float f) {
  bf16 h = __float2bfloat16(f);
  u16 s;
  __builtin_memcpy(&s, &h, 2);
  return s;
}
static __device__ __forceinline__ float ldf(const void* p, size_t i, int f32) {
  return f32 ? ((const float*)p)[i] : bs2f(((const u16*)p)[i]);
}

// ---------------------------------------------------------------------------
// dtype detection on a 256 KB sample of x.
// ---------------------------------------------------------------------------
__global__ __launch_bounds__(256) void detect_dtype(const uint4* __restrict__ xs,
                                                    int* __restrict__ flag) {
  int i = blockIdx.x * 256 + threadIdx.x;
  uint4 v = xs[i];
  bool hit = false;
#pragma unroll
  for (int j = 0; j < 4; ++j) {
    unsigned w = (j == 0) ? v.x : (j == 1) ? v.y : (j == 2) ? v.z : v.w;
    if ((w & 0x7F80u) == 0x7F80u) hit = true;
    if ((w & 0x7F800000u) == 0x7F800000u) hit = true;
  }
  unsigned long long mask = __ballot(hit);
  if (mask != 0ull && (threadIdx.x & 63) == 0) atomicOr(flag, 1);
}

// one-time gate weights conversion -> bf16 gwb[64][128], f32 gbf[64]
__global__ __launch_bounds__(256) void prep_gate(
    const void* __restrict__ gate_w, const void* __restrict__ gate_b,
    u16* __restrict__ gwb, float* __restrict__ gbf,
    const int* __restrict__ dtf) {
  const int f32 = *dtf;
  int t = threadIdx.x;
  for (int i = t; i < 8192; i += 256)
    gwb[i] = f32 ? f2bs(((const float*)gate_w)[i]) : ((const u16*)gate_w)[i];
  if (t < 64) gbf[t] = ldf(gate_b, t, f32);
}

// ---------------------------------------------------------------------------
// transpose [b][c=512][N] -> [b][N][512] bf16; optional fused heat partials.
// ---------------------------------------------------------------------------
__global__ __launch_bounds__(256) void transpose_bf16(
    const void* __restrict__ src, u16* __restrict__ dst, int N,
    float* __restrict__ heat, const int* __restrict__ dtf) {
  const int f32 = *dtf;
  const int b = blockIdx.z, n0 = blockIdx.x * 64, c0 = blockIdx.y * 64;
  const int t = threadIdx.x;
  __shared__ __align__(16) u16 tile[64][72];
#pragma unroll
  for (int j = 0; j < 2; ++j) {
    int cc = (t >> 3) + j * 32;
    int nn = (t & 7) * 8;
    u16 tmp[8];
    if (f32) {
      const float* s4 = (const float*)src + ((size_t)(b * 512 + c0 + cc)) * N + n0 + nn;
#pragma unroll
      for (int u = 0; u < 8; ++u) tmp[u] = f2bs(s4[u]);
    } else {
      *reinterpret_cast<uint4*>(tmp) = *reinterpret_cast<const uint4*>(
          (const u16*)src + ((size_t)(b * 512 + c0 + cc)) * N + n0 + nn);
    }
    *reinterpret_cast<uint4*>(&tile[cc][nn]) = *reinterpret_cast<const uint4*>(tmp);
  }
  __syncthreads();
  if (heat != nullptr && t < 32) {
    float s = 0.f;
#pragma unroll 8
    for (int cc = 0; cc < 64; ++cc)
      s += bs2f(tile[cc][2 * t]) + bs2f(tile[cc][2 * t + 1]);
    int y = blockIdx.x;
    atomicAdd(&heat[b * 1024 + (y >> 1) * 32 + t], s);
  }
#pragma unroll
  for (int j = 0; j < 2; ++j) {
    int nn = (t >> 3) + j * 32;
    int cc0 = (t & 7) * 8;
    u16 tmp[8];
#pragma unroll
    for (int u = 0; u < 8; ++u) tmp[u] = tile[cc0 + u][nn];
    *reinterpret_cast<uint4*>(&dst[((size_t)b * N + n0 + nn) * 512 + c0 + cc0]) =
        *reinterpret_cast<const uint4*>(tmp);
  }
}

// ---------------------------------------------------------------------------
// 128m x 64o MFMA conv1x1 GEMM (r13-proven: LDS dbuf + register prefetch in
// NAMED uint4 SCALARS, straight-line. 1 barrier/K-step; store-prefetch sits
// between the two ks halves. Grid (32,8,2) = 2 blocks/CU: named-scalar dbuf
// + cross-block TLP is the measured sweet spot (r15's 1-block/CU 128-o-tile
// widening regressed ~5.5us). MODE 0 (q): outputs scaled by 0.125.
// ---------------------------------------------------------------------------
template<int MODE>
__global__ __launch_bounds__(256) void gemm128(
    const u16* __restrict__ A, const void* __restrict__ W,
    const void* __restrict__ bias, u16* __restrict__ o0,
    void* __restrict__ ob, float* __restrict__ qsum, int M,
    const int* __restrict__ dtf) {
  const int f32 = *dtf;
  const int b = blockIdx.z, m0 = blockIdx.x * 128, oo0 = blockIdx.y * 64;
  const int t = threadIdx.x, w = t >> 6, lane = t & 63;
  const int quad = lane >> 4, c = lane & 15;
  __shared__ __align__(16) u16 As[2][128][72];
  __shared__ __align__(16) u16 Ws[2][64][72];
  f32x4 acc[2][4];
#pragma unroll
  for (int nt = 0; nt < 2; ++nt)
#pragma unroll
    for (int ot = 0; ot < 4; ++ot) acc[nt][ot] = (f32x4){0.f, 0.f, 0.f, 0.f};
  const u16* Ab = A + (size_t)b * M * 512;
  const int arow = t >> 1, acol = (t & 1) * 32;
  const int wrow = t >> 2, wcol = (t & 3) * 16;

  uint4 ar0, ar1, ar2, ar3, wr0, wr1, wr2, wr3;

  {
    const uint4* gs = reinterpret_cast<const uint4*>(Ab + (size_t)(m0 + arow) * 512 + acol);
    uint4* ad = reinterpret_cast<uint4*>(&As[0][arow][acol]);
    ad[0] = gs[0]; ad[1] = gs[1]; ad[2] = gs[2]; ad[3] = gs[3];
    if (f32) {
      const float* gw = (const float*)W + (size_t)(oo0 + wrow) * 512 + wcol;
#pragma unroll
      for (int e = 0; e < 16; ++e) Ws[0][wrow][wcol + e] = f2bs(gw[e]);
    } else {
      const u16* gw = (const u16*)W + (size_t)(oo0 + wrow) * 512 + wcol;
      *reinterpret_cast<uint4*>(&Ws[0][wrow][wcol])     = *reinterpret_cast<const uint4*>(gw);
      *reinterpret_cast<uint4*>(&Ws[0][wrow][wcol + 8]) = *reinterpret_cast<const uint4*>(gw + 8);
    }
    const uint4* gs1 = reinterpret_cast<const uint4*>(Ab + (size_t)(m0 + arow) * 512 + 64 + acol);
    ar0 = gs1[0]; ar1 = gs1[1]; ar2 = gs1[2]; ar3 = gs1[3];
    if (f32) {
      const uint4* gw = reinterpret_cast<const uint4*>(
          (const float*)W + (size_t)(oo0 + wrow) * 512 + 64 + wcol);
      wr0 = gw[0]; wr1 = gw[1]; wr2 = gw[2]; wr3 = gw[3];
    } else {
      const uint4* gw = reinterpret_cast<const uint4*>(
          (const u16*)W + (size_t)(oo0 + wrow) * 512 + 64 + wcol);
      wr0 = gw[0]; wr1 = gw[1];
    }
  }

  for (int ki = 0; ki < 8; ++ki) {
    __syncthreads();
    const int bf = ki & 1;

    // ks = 0 half
    {
      bf16x8 av0 = *reinterpret_cast<const bf16x8*>(&As[bf][w * 32 + c][quad * 8]);
      bf16x8 av1 = *reinterpret_cast<const bf16x8*>(&As[bf][w * 32 + 16 + c][quad * 8]);
#pragma unroll
      for (int ot = 0; ot < 4; ++ot) {
        bf16x8 wv = *reinterpret_cast<const bf16x8*>(&Ws[bf][ot * 16 + c][quad * 8]);
        if (MODE == 3) {
          acc[0][ot] = __builtin_amdgcn_mfma_f32_16x16x32_bf16(wv, av0, acc[0][ot], 0, 0, 0);
          acc[1][ot] = __builtin_amdgcn_mfma_f32_16x16x32_bf16(wv, av1, acc[1][ot], 0, 0, 0);
        } else {
          acc[0][ot] = __builtin_amdgcn_mfma_f32_16x16x32_bf16(av0, wv, acc[0][ot], 0, 0, 0);
          acc[1][ot] = __builtin_amdgcn_mfma_f32_16x16x32_bf16(av1, wv, acc[1][ot], 0, 0, 0);
        }
      }
    }

    if (ki + 1 < 8) {
      uint4* ad = reinterpret_cast<uint4*>(&As[bf ^ 1][arow][acol]);
      ad[0] = ar0; ad[1] = ar1; ad[2] = ar2; ad[3] = ar3;
      if (f32) {
        float tf[16];
        __builtin_memcpy(&tf[0],  &wr0, 16);
        __builtin_memcpy(&tf[4],  &wr1, 16);
        __builtin_memcpy(&tf[8],  &wr2, 16);
        __builtin_memcpy(&tf[12], &wr3, 16);
#pragma unroll
        for (int e = 0; e < 16; ++e) Ws[bf ^ 1][wrow][wcol + e] = f2bs(tf[e]);
      } else {
        *reinterpret_cast<uint4*>(&Ws[bf ^ 1][wrow][wcol])     = wr0;
        *reinterpret_cast<uint4*>(&Ws[bf ^ 1][wrow][wcol + 8]) = wr1;
      }
      if (ki + 2 < 8) {
        const int k0 = (ki + 2) * 64;
        const uint4* gs = reinterpret_cast<const uint4*>(Ab + (size_t)(m0 + arow) * 512 + k0 + acol);
        ar0 = gs[0]; ar1 = gs[1]; ar2 = gs[2]; ar3 = gs[3];
        if (f32) {
          const uint4* gw = reinterpret_cast<const uint4*>(
              (const float*)W + (size_t)(oo0 + wrow) * 512 + k0 + wcol);
          wr0 = gw[0]; wr1 = gw[1]; wr2 = gw[2]; wr3 = gw[3];
        } else {
          const uint4* gw = reinterpret_cast<const uint4*>(
              (const u16*)W + (size_t)(oo0 + wrow) * 512 + k0 + wcol);
          wr0 = gw[0]; wr1 = gw[1];
        }
      }
    }

    // ks = 1 half
    {
      bf16x8 av0 = *reinterpret_cast<const bf16x8*>(&As[bf][w * 32 + c][32 + quad * 8]);
      bf16x8 av1 = *reinterpret_cast<const bf16x8*>(&As[bf][w * 32 + 16 + c][32 + quad * 8]);
#pragma unroll
      for (int ot = 0; ot < 4; ++ot) {
        bf16x8 wv = *reinterpret_cast<const bf16x8*>(&Ws[bf][ot * 16 + c][32 + quad * 8]);
        if (MODE == 3) {
          acc[0][ot] = __builtin_amdgcn_mfma_f32_16x16x32_bf16(wv, av0, acc[0][ot], 0, 0, 0);
          acc[1][ot] = __builtin_amdgcn_mfma_f32_16x16x32_bf16(wv, av1, acc[1][ot], 0, 0, 0);
        } else {
          acc[0][ot] = __builtin_amdgcn_mfma_f32_16x16x32_bf16(av0, wv, acc[0][ot], 0, 0, 0);
          acc[1][ot] = __builtin_amdgcn_mfma_f32_16x16x32_bf16(av1, wv, acc[1][ot], 0, 0, 0);
        }
      }
    }
  }

  if (MODE == 0) {
    const int h = oo0 >> 6, bh = b * 8 + h;
#pragma unroll
    for (int ot = 0; ot < 4; ++ot) {
      int o = oo0 + ot * 16 + c;
      int d = o & 63;
      float bv = ldf(bias, o, f32);
      float qs = 0.f;
#pragma unroll
      for (int nt = 0; nt < 2; ++nt)
#pragma unroll
        for (int r = 0; r < 4; ++r) {
          int m = m0 + w * 32 + nt * 16 + quad * 4 + r;
          float qv = acc[nt][ot][r] + bv;
          o0[((size_t)bh * M + m) * 64 + d] = f2bs(qv * 0.125f);
          qs += qv;
        }
      qs += __shfl_xor(qs, 16, 64);
      qs += __shfl_xor(qs, 32, 64);
      if (quad == 0) atomicAdd(&qsum[bh * 64 + d], qs);
    }
  } else {
#pragma unroll
    for (int ot = 0; ot < 4; ++ot)
#pragma unroll
      for (int r = 0; r < 4; ++r) {
        int o = oo0 + ot * 16 + quad * 4 + r;
        float bv = ldf(bias, o, f32);
#pragma unroll
        for (int nt = 0; nt < 2; ++nt) {
          int m = m0 + w * 32 + nt * 16 + c;
          float val = acc[nt][ot][r] + bv;
          size_t oi_ = ((size_t)(b * 512 + o)) * M + m;
          if (f32) ((float*)ob)[oi_] = val;
          else     ((u16*)ob)[oi_] = f2bs(val);
        }
      }
  }
}

// ---------------------------------------------------------------------------
// 64x64 MFMA conv1x1 GEMM for kv_up (r13-proven dbuf + named-scalar prefetch,
// 1 barrier/K-step). kb [bh][m][64], v2 swizzled.
// v2 index for V[d][m] (per bh): ((ch*2+s)*4+dt)*512 + (q2*16+cc)*8 + e
// ---------------------------------------------------------------------------
__global__ __launch_bounds__(256) void gemm_kv(
    const u16* __restrict__ A, const void* __restrict__ W,
    const void* __restrict__ bias, u16* __restrict__ kb, u16* __restrict__ v2,
    int M, const int* __restrict__ dtf) {
  const int f32 = *dtf;
  const int b = blockIdx.z, m0 = blockIdx.x * 64, oo0 = blockIdx.y * 64;
  const int t = threadIdx.x, w = t >> 6, lane = t & 63;
  const int quad = lane >> 4, c = lane & 15;
  __shared__ __align__(16) u16 As[2][64][72];
  __shared__ __align__(16) u16 Ws[2][64][72];
  f32x4 acc[4];
#pragma unroll
  for (int ot = 0; ot < 4; ++ot) acc[ot] = (f32x4){0.f, 0.f, 0.f, 0.f};
  const u16* Ab = A + (size_t)b * M * 512;
  const int srow = t >> 2, scol = (t & 3) * 16;

  uint4 ar0, ar1, wr0, wr1, wr2, wr3;

  {
    const uint4* gs = reinterpret_cast<const uint4*>(Ab + (size_t)(m0 + srow) * 512 + scol);
    *reinterpret_cast<uint4*>(&As[0][srow][scol])     = gs[0];
    *reinterpret_cast<uint4*>(&As[0][srow][scol + 8]) = gs[1];
    if (f32) {
      const float* gw = (const float*)W + (size_t)(oo0 + srow) * 512 + scol;
#pragma unroll
      for (int e = 0; e < 16; ++e) Ws[0][srow][scol + e] = f2bs(gw[e]);
    } else {
      const u16* gw = (const u16*)W + (size_t)(oo0 + srow) * 512 + scol;
      *reinterpret_cast<uint4*>(&Ws[0][srow][scol])     = *reinterpret_cast<const uint4*>(gw);
      *reinterpret_cast<uint4*>(&Ws[0][srow][scol + 8]) = *reinterpret_cast<const uint4*>(gw + 8);
    }
    const uint4* gs1 = reinterpret_cast<const uint4*>(Ab + (size_t)(m0 + srow) * 512 + 64 + scol);
    ar0 = gs1[0]; ar1 = gs1[1];
    if (f32) {
      const uint4* gw = reinterpret_cast<const uint4*>(
          (const float*)W + (size_t)(oo0 + srow) * 512 + 64 + scol);
      wr0 = gw[0]; wr1 = gw[1]; wr2 = gw[2]; wr3 = gw[3];
    } else {
      const uint4* gw = reinterpret_cast<const uint4*>(
          (const u16*)W + (size_t)(oo0 + srow) * 512 + 64 + scol);
      wr0 = gw[0]; wr1 = gw[1];
    }
  }

  for (int ki = 0; ki < 8; ++ki) {
    __syncthreads();
    const int bf = ki & 1;

    {
      bf16x8 av = *reinterpret_cast<const bf16x8*>(&As[bf][w * 16 + c][quad * 8]);
#pragma unroll
      for (int ot = 0; ot < 4; ++ot) {
        bf16x8 wv = *reinterpret_cast<const bf16x8*>(&Ws[bf][ot * 16 + c][quad * 8]);
        acc[ot] = __builtin_amdgcn_mfma_f32_16x16x32_bf16(av, wv, acc[ot], 0, 0, 0);
      }
    }

    if (ki + 1 < 8) {
      *reinterpret_cast<uint4*>(&As[bf ^ 1][srow][scol])     = ar0;
      *reinterpret_cast<uint4*>(&As[bf ^ 1][srow][scol + 8]) = ar1;
      if (f32) {
        float tf[16];
        __builtin_memcpy(&tf[0],  &wr0, 16);
        __builtin_memcpy(&tf[4],  &wr1, 16);
        __builtin_memcpy(&tf[8],  &wr2, 16);
        __builtin_memcpy(&tf[12], &wr3, 16);
#pragma unroll
        for (int e = 0; e < 16; ++e) Ws[bf ^ 1][srow][scol + e] = f2bs(tf[e]);
      } else {
        *reinterpret_cast<uint4*>(&Ws[bf ^ 1][srow][scol])     = wr0;
        *reinterpret_cast<uint4*>(&Ws[bf ^ 1][srow][scol + 8]) = wr1;
      }
      if (ki + 2 < 8) {
        const int k0 = (ki + 2) * 64;
        const uint4* gs = reinterpret_cast<const uint4*>(Ab + (size_t)(m0 + srow) * 512 + k0 + scol);
        ar0 = gs[0]; ar1 = gs[1];
        if (f32) {
          const uint4* gw = reinterpret_cast<const uint4*>(
              (const float*)W + (size_t)(oo0 + srow) * 512 + k0 + scol);
          wr0 = gw[0]; wr1 = gw[1]; wr2 = gw[2]; wr3 = gw[3];
        } else {
          const uint4* gw = reinterpret_cast<const uint4*>(
              (const u16*)W + (size_t)(oo0 + srow) * 512 + k0 + scol);
          wr0 = gw[0]; wr1 = gw[1];
        }
      }
    }

    {
      bf16x8 av = *reinterpret_cast<const bf16x8*>(&As[bf][w * 16 + c][32 + quad * 8]);
#pragma unroll
      for (int ot = 0; ot < 4; ++ot) {
        bf16x8 wv = *reinterpret_cast<const bf16x8*>(&Ws[bf][ot * 16 + c][32 + quad * 8]);
        acc[ot] = __builtin_amdgcn_mfma_f32_16x16x32_bf16(av, wv, acc[ot], 0, 0, 0);
      }
    }
  }

#pragma unroll
  for (int ot = 0; ot < 4; ++ot) {
    int o = oo0 + ot * 16 + c;
    float bv = ldf(bias, o, f32);
    int hh = o >> 7, jj = o & 127;
#pragma unroll
    for (int r = 0; r < 4; ++r) {
      int m = m0 + w * 16 + quad * 4 + r;
      u16 val = f2bs(acc[ot][r] + bv);
      if (jj < 64) {
        kb[((size_t)(b * 8 + hh) * M + m) * 64 + jj] = val;
      } else {
        int d = jj & 63;
        v2[((((size_t)(b * 8 + hh) * 16 + (m >> 6)) * 2 + ((m >> 5) & 1)) * 4 + (d >> 4)) * 512
           + (((m >> 3) & 3) * 16 + (d & 15)) * 8 + (m & 7)] = val;
      }
    }
  }
}

// ---------------------------------------------------------------------------
// scores -> top-16 coarse cells -> 64 full-res positions into posb.
// Vectorized score loads (8 x uint4/row); per-wave shfl_xor selection.
// ---------------------------------------------------------------------------
__global__ __launch_bounds__(256) void topk_kernel(
    const float* __restrict__ qsum, const u16* __restrict__ k,
    const float* __restrict__ heat, const void* __restrict__ gumbel,
    int* __restrict__ posb, const int* __restrict__ dtf) {
  const int f32 = *dtf;
  int bh = blockIdx.x, b = bh >> 3, t = threadIdx.x;
  const int lane = t & 63, w = t >> 6;
  __shared__ float qs[64];
  __shared__ float s[1024];
  __shared__ float rv[4];
  __shared__ int   ri[4];
  if (t < 64) qs[t] = qsum[bh * 64 + t];
  __syncthreads();
  for (int j = 0; j < 4; ++j) {
    int m = t + j * 256;
    const uint4* kr = reinterpret_cast<const uint4*>(k + ((size_t)bh * 1024 + m) * 64);
    float dot = 0.f;
#pragma unroll
    for (int v = 0; v < 8; ++v) {
      uint4 kq = kr[v];
      u16 tmp[8];
      *reinterpret_cast<uint4*>(tmp) = kq;
#pragma unroll
      for (int e = 0; e < 8; ++e) dot += qs[v * 8 + e] * bs2f(tmp[e]);
    }
    s[m] = dot * (0.125f / 4096.0f) * (heat[b * 1024 + m] * (1.0f / 2048.0f)) +
           ldf(gumbel, (size_t)bh * 1024 + m, f32);
  }
  __syncthreads();
  for (int it = 0; it < 16; ++it) {
    float bv = -1e30f; int bi = 0x7fffffff;
    for (int j = 0; j < 4; ++j) {
      int m = t + j * 256; float vv = s[m];
      if (vv > bv || (vv == bv && m < bi)) { bv = vv; bi = m; }
    }
#pragma unroll
    for (int off = 1; off < 64; off <<= 1) {
      float ov = __shfl_xor(bv, off, 64);
      int   oi = __shfl_xor(bi, off, 64);
      if (ov > bv || (ov == bv && oi < bi)) { bv = ov; bi = oi; }
    }
    if (lane == 0) { rv[w] = bv; ri[w] = bi; }
    __syncthreads();
    if (t == 0) {
      float fv = rv[0]; int fi = ri[0];
#pragma unroll
      for (int ww = 1; ww < 4; ++ww)
        if (rv[ww] > fv || (rv[ww] == fv && ri[ww] < fi)) { fv = rv[ww]; fi = ri[ww]; }
      s[fi] = -1e30f;
      int hy = (fi >> 5) * 2, wx = (fi & 31) * 2;
      posb[bh * 64 + it]      = hy * 64 + wx;
      posb[bh * 64 + 16 + it] = hy * 64 + wx + 1;
      posb[bh * 64 + 32 + it] = (hy + 1) * 64 + wx;
      posb[bh * 64 + 48 + it] = (hy + 1) * 64 + wx + 1;
    }
    __syncthreads();
  }
}

// ---------------------------------------------------------------------------
// gather_kv as MFMA GEMM (r14-proven named-scalar dbuf, 1 barrier/K-step).
// ---------------------------------------------------------------------------
__global__ __launch_bounds__(256) void gather_kv_mfma(
    const u16* __restrict__ xT, const void* __restrict__ kv_w,
    const void* __restrict__ kv_b, const int* __restrict__ posb,
    u16* __restrict__ tkb, u16* __restrict__ tvTb,
    const int* __restrict__ dtf) {
  const int f32 = *dtf;
  const int bh = blockIdx.x, b = bh >> 3, h = bh & 7;
  const int half = blockIdx.y;
  const int t = threadIdx.x, w = t >> 6, lane = t & 63;
  const int quad = lane >> 4, c = lane & 15;
  __shared__ int pos[64];
  __shared__ __align__(16) u16 As[2][64][72];
  __shared__ __align__(16) u16 Ws[2][64][72];
  if (t < 64) pos[t] = posb[bh * 64 + t];
  __syncthreads();
  const int obase = h * 128 + half * 64;
  const int srow = t >> 2, scol = (t & 3) * 16;
  const int arow = pos[srow];
  const u16* Ab = xT + ((size_t)b * 4096 + arow) * 512;
  f32x4 acc[4];
#pragma unroll
  for (int ot = 0; ot < 4; ++ot) acc[ot] = (f32x4){0.f, 0.f, 0.f, 0.f};

  uint4 ar0, ar1, wr0, wr1, wr2, wr3;

  {
    const uint4* gs = reinterpret_cast<const uint4*>(Ab + scol);
    *reinterpret_cast<uint4*>(&As[0][srow][scol])     = gs[0];
    *reinterpret_cast<uint4*>(&As[0][srow][scol + 8]) = gs[1];
    if (f32) {
      const float* gw = (const float*)kv_w + (size_t)(obase + srow) * 512 + scol;
#pragma unroll
      for (int e = 0; e < 16; ++e) Ws[0][srow][scol + e] = f2bs(gw[e]);
    } else {
      const u16* gw = (const u16*)kv_w + (size_t)(obase + srow) * 512 + scol;
      *reinterpret_cast<uint4*>(&Ws[0][srow][scol])     = *reinterpret_cast<const uint4*>(gw);
      *reinterpret_cast<uint4*>(&Ws[0][srow][scol + 8]) = *reinterpret_cast<const uint4*>(gw + 8);
    }
    const uint4* gs1 = reinterpret_cast<const uint4*>(Ab + 64 + scol);
    ar0 = gs1[0]; ar1 = gs1[1];
    if (f32) {
      const uint4* gw = reinterpret_cast<const uint4*>(
          (const float*)kv_w + (size_t)(obase + srow) * 512 + 64 + scol);
      wr0 = gw[0]; wr1 = gw[1]; wr2 = gw[2]; wr3 = gw[3];
    } else {
      const uint4* gw = reinterpret_cast<const uint4*>(
          (const u16*)kv_w + (size_t)(obase + srow) * 512 + 64 + scol);
      wr0 = gw[0]; wr1 = gw[1];
    }
  }

  for (int ki = 0; ki < 8; ++ki) {
    __syncthreads();
    const int bf = ki & 1;

    {
      bf16x8 av = *reinterpret_cast<const bf16x8*>(&As[bf][w * 16 + c][quad * 8]);
#pragma unroll
      for (int ot = 0; ot < 4; ++ot) {
        bf16x8 wv = *reinterpret_cast<const bf16x8*>(&Ws[bf][ot * 16 + c][quad * 8]);
        acc[ot] = __builtin_amdgcn_mfma_f32_16x16x32_bf16(av, wv, acc[ot], 0, 0, 0);
      }
    }

    if (ki + 1 < 8) {
      *reinterpret_cast<uint4*>(&As[bf ^ 1][srow][scol])     = ar0;
      *reinterpret_cast<uint4*>(&As[bf ^ 1][srow][scol + 8]) = ar1;
      if (f32) {
        float tf[16];
        __builtin_memcpy(&tf[0],  &wr0, 16);
        __builtin_memcpy(&tf[4],  &wr1, 16);
        __builtin_memcpy(&tf[8],  &wr2, 16);
        __builtin_memcpy(&tf[12], &wr3, 16);
#pragma unroll
        for (int e = 0; e < 16; ++e) Ws[bf ^ 1][srow][scol + e] = f2bs(tf[e]);
      } else {
        *reinterpret_cast<uint4*>(&Ws[bf ^ 1][srow][scol])     = wr0;
        *reinterpret_cast<uint4*>(&Ws[bf ^ 1][srow][scol + 8]) = wr1;
      }
      if (ki + 2 < 8) {
        const int k0 = (ki + 2) * 64;
        const uint4* gs = reinterpret_cast<const uint4*>(Ab + k0 + scol);
        ar0 = gs[0]; ar1 = gs[1];
        if (f32) {
          const uint4* gw = reinterpret_cast<const uint4*>(
              (const float*)kv_w + (size_t)(obase + srow) * 512 + k0 + scol);
          wr0 = gw[0]; wr1 = gw[1]; wr2 = gw[2]; wr3 = gw[3];
        } else {
          const uint4* gw = reinterpret_cast<const uint4*>(
              (const u16*)kv_w + (size_t)(obase + srow) * 512 + k0 + scol);
          wr0 = gw[0]; wr1 = gw[1];
        }
      }
    }

    {
      bf16x8 av = *reinterpret_cast<const bf16x8*>(&As[bf][w * 16 + c][32 + quad * 8]);
#pragma unroll
      for (int ot = 0; ot < 4; ++ot) {
        bf16x8 wv = *reinterpret_cast<const bf16x8*>(&Ws[bf][ot * 16 + c][32 + quad * 8]);
        acc[ot] = __builtin_amdgcn_mfma_f32_16x16x32_bf16(av, wv, acc[ot], 0, 0, 0);
      }
    }
  }

#pragma unroll
  for (int ot = 0; ot < 4; ++ot) {
    int d = ot * 16 + c;
    float bv = ldf(kv_b, obase + d, f32);
#pragma unroll
    for (int r = 0; r < 4; ++r) {
      int m = w * 16 + quad * 4 + r;
      u16 val = f2bs(acc[ot][r] + bv);
      if (half) tvTb[((size_t)bh * 64 + d) * 64 + m] = val;
      else      tkb[((size_t)bh * 64 + m) * 64 + d] = val;
    }
  }
}

// ---------------------------------------------------------------------------
// depthwise 7x7 conv on v (v2 swizzled layout) -> vpe bf16 (strip structure:
// 4-row column strip per thread, weights in regs, row segments reused across
// output rows; DS reads/thread 392 -> ~119).
// ---------------------------------------------------------------------------
__global__ __launch_bounds__(256) void dwconv_kernel(
    const u16* __restrict__ v2, const void* __restrict__ pe_w,
    const void* __restrict__ pe_b, u16* __restrict__ vpe,
    const int* __restrict__ dtf) {
  const int f32 = *dtf;
  int bc = blockIdx.x;
  int b = bc >> 9, c = bc & 511;
  int h = c >> 6, d = c & 63;
  int dt = d >> 4, cc = d & 15;
  int t = threadIdx.x;
  __shared__ float img[1024];
  __shared__ float wts[49];
  if (t < 128) {
    int ch = t >> 3, s = (t >> 2) & 1, q2 = t & 3;
    const u16* src = v2 + ((((size_t)(b * 8 + h) * 16 + ch) * 2 + s) * 4 + dt) * 512
                        + (q2 * 16 + cc) * 8;
    uint4 v4 = *reinterpret_cast<const uint4*>(src);
    u16 tmp[8];
    *reinterpret_cast<uint4*>(tmp) = v4;
#pragma unroll
    for (int e = 0; e < 8; ++e) img[t * 8 + e] = bs2f(tmp[e]);
  }
  if (t < 49) wts[t] = ldf(pe_w, c * 49 + t, f32);
  float bias = ldf(pe_b, c, f32);
  __syncthreads();

  float wreg[49];
#pragma unroll
  for (int i = 0; i < 49; ++i) wreg[i] = wts[i];

  const int x = t & 31, y0 = (t >> 5) * 4;
  float acc[4] = {0.f, 0.f, 0.f, 0.f};
#pragma unroll
  for (int r = 0; r < 10; ++r) {
    int yy = y0 - 3 + r;
    if ((unsigned)yy >= 32u) continue;
    float rr[7];
#pragma unroll
    for (int j = 0; j < 7; ++j) {
      int xc = x - 3 + j;
      rr[j] = ((unsigned)xc < 32u) ? img[yy * 32 + xc] : 0.f;
    }
#pragma unroll
    for (int p = 0; p < 4; ++p) {
      int ky = r - p;                 // yy = (y0+p) + ky - 3
      if (ky < 0 || ky > 6) continue;
      float s2 = 0.f;
#pragma unroll
      for (int j = 0; j < 7; ++j) s2 += rr[j] * wreg[ky * 7 + j];
      acc[p] += s2;
    }
  }
#pragma unroll
  for (int p = 0; p < 4; ++p)
    vpe[(size_t)bc * 1024 + (y0 + p) * 32 + x] = f2bs(acc[p] + bias);
}

// ---------------------------------------------------------------------------
// FUSED coarse+fine attention (r6/r10 structure + round-17 XCD-aware bh
// grouping). Grid stays (64,16); the linear dispatch id (bx fastest) is
// remapped BIJECTIVELY so each XCD (id%8 round-robin, m09) owns 2 bh values
// across all 64 bx blocks: per-XCD K/V+vpe working set 6MB -> ~768KB << 4MB
// L2. V is register-direct with in-chunk issue distance (~L2 latency only),
// so keeping V loads L2-resident removes HBM-latency stalls at PV.
// Pure relabeling: no correctness impact.
// ---------------------------------------------------------------------------
__global__ __launch_bounds__(256, 4) void attn_fused(
    const u16* __restrict__ q, const u16* __restrict__ k,
    const u16* __restrict__ v2, const u16* __restrict__ tkb,
    const u16* __restrict__ tvTb, const u16* __restrict__ gwb,
    const float* __restrict__ gbf, const u16* __restrict__ vpe,
    u16* __restrict__ xsT) {
  // XCD-aware remap: id = bx + 64*bh (hw linear, .x fastest); xcd = id&7.
  const int id = blockIdx.x + (blockIdx.y << 6);
  const int xcd = id & 7, slot = id >> 3;
  const int bh = 2 * xcd + (slot >> 6);
  const int bx = slot & 63;
  const int b = bh >> 3, h = bh & 7;
  const int n0 = bx * 64;
  const int t = threadIdx.x, w = t >> 6, lane = t & 63;
  const int quad = lane >> 4, c = lane & 15;

  __shared__ __align__(16) u16 lds[13824];   // 27.6 KB union
  u16* Ks = lds;              // [2][64][72] K double-buffer
  u16* Ps = lds + 9216;       // [4][16][72] per-wave P tiles

  // ---- phase A: coarse ----
  bf16x8 bq[2];
  {
    const u16* qr = q + ((size_t)bh * 4096 + n0 + w * 16 + c) * 64;
    bq[0] = *reinterpret_cast<const bf16x8*>(qr + quad * 8);
    bq[1] = *reinterpret_cast<const bf16x8*>(qr + 32 + quad * 8);
  }
  f32x4 po[4];
#pragma unroll
  for (int dt = 0; dt < 4; ++dt) po[dt] = (f32x4){0.f, 0.f, 0.f, 0.f};
  float sume = 0.f;

  const u16* kbase = k + (size_t)bh * 65536;
  const u16* v2base = v2 + (size_t)bh * 65536;
  const int srow = t >> 2, scol = (t & 3) * 16;

  uint4 kr0, kr1;
  {
    // chunk 0 staged directly into buf 0
    const u16* gk = kbase + (size_t)srow * 64 + scol;
    kr0 = *reinterpret_cast<const uint4*>(gk);
    kr1 = *reinterpret_cast<const uint4*>(gk + 8);
    *reinterpret_cast<uint4*>(&Ks[srow * 72 + scol])     = kr0;
    *reinterpret_cast<uint4*>(&Ks[srow * 72 + scol + 8]) = kr1;
    // prefetch chunk 1 into regs
    const u16* gk1 = kbase + (size_t)(64 + srow) * 64 + scol;
    kr0 = *reinterpret_cast<const uint4*>(gk1);
    kr1 = *reinterpret_cast<const uint4*>(gk1 + 8);
  }

  for (int ch = 0; ch < 16; ++ch) {
    __syncthreads();
    const int buf = ch & 1;

    // V fragments: coalesced register-direct loads (consumed at PV)
    bf16x8 av[4][2];
    {
      const u16* v2c = v2base + (size_t)ch * 4096;
#pragma unroll
      for (int dt = 0; dt < 4; ++dt) {
        av[dt][0] = *reinterpret_cast<const bf16x8*>(v2c + dt * 512 + lane * 8);
        av[dt][1] = *reinterpret_cast<const bf16x8*>(v2c + 2048 + dt * 512 + lane * 8);
      }
    }

    // QK from LDS K buffer
    f32x4 st[4];
#pragma unroll
    for (int mt = 0; mt < 4; ++mt) {
      const u16* krow = &Ks[buf * 4608 + (mt * 16 + c) * 72];
      bf16x8 ak0 = *reinterpret_cast<const bf16x8*>(krow + quad * 8);
      bf16x8 ak1 = *reinterpret_cast<const bf16x8*>(krow + 32 + quad * 8);
      f32x4 acc = (f32x4){0.f, 0.f, 0.f, 0.f};
      acc = __builtin_amdgcn_mfma_f32_16x16x32_bf16(ak0, bq[0], acc, 0, 0, 0);
      acc = __builtin_amdgcn_mfma_f32_16x16x32_bf16(ak1, bq[1], acc, 0, 0, 0);
      st[mt] = acc;
    }

    // stage prefetched K into other buffer; prefetch ch+2
    if (ch + 1 < 16) {
      *reinterpret_cast<uint4*>(&Ks[(buf ^ 1) * 4608 + srow * 72 + scol])     = kr0;
      *reinterpret_cast<uint4*>(&Ks[(buf ^ 1) * 4608 + srow * 72 + scol + 8]) = kr1;
      if (ch + 2 < 16) {
        const u16* gk = kbase + (size_t)((ch + 2) * 64 + srow) * 64 + scol;
        kr0 = *reinterpret_cast<const uint4*>(gk);
        kr1 = *reinterpret_cast<const uint4*>(gk + 8);
      }
    }

    // softmax numerator (q pre-scaled; raw exp)
    float cs = 0.f;
    u16* psw = &Ps[(w * 16 + c) * 72];
#pragma unroll
    for (int mt = 0; mt < 4; ++mt) {
      float e0 = __expf(st[mt][0]);
      float e1 = __expf(st[mt][1]);
      float e2 = __expf(st[mt][2]);
      float e3 = __expf(st[mt][3]);
      cs += (e0 + e1) + (e2 + e3);
      ushort4 pw;
      pw.x = f2bs(e0); pw.y = f2bs(e1); pw.z = f2bs(e2); pw.w = f2bs(e3);
      *reinterpret_cast<ushort4*>(psw + mt * 16 + quad * 4) = pw;
    }
    cs += __shfl_xor(cs, 16, 64);
    cs += __shfl_xor(cs, 32, 64);
    sume += cs;

    // PV
#pragma unroll
    for (int s = 0; s < 2; ++s) {
      bf16x8 bp = *reinterpret_cast<const bf16x8*>(psw + s * 32 + quad * 8);
#pragma unroll
      for (int dt = 0; dt < 4; ++dt) {
        po[dt] = __builtin_amdgcn_mfma_f32_16x16x32_bf16(av[dt][s], bp, po[dt], 0, 0, 0);
      }
    }
  }

  __syncthreads();  // phase A LDS dead; repartition
  u16* fus = lds;                       // [4][16][136]
  u16* vl  = lds + 8704;                // [2][64][36]
  float* gbl = (float*)(lds + 13312);   // [64]

  // block-uniform bilinear y setup (all rows of this block have y = bx)
  const int ym = bx >> 1;
  int r0_, r1_; float wy0, wy1;
  if ((bx & 1) == 0) { r0_ = ym > 0 ? ym - 1 : 0; r1_ = ym; wy0 = 0.25f; wy1 = 0.75f; }
  else               { r0_ = ym; r1_ = ym < 31 ? ym + 1 : 31; wy0 = 0.75f; wy1 = 0.25f; }

  for (int idx = t; idx < 512; idx += 256) {
    int seg = idx & 3, ch2 = (idx >> 2) & 63, rr = idx >> 8;
    int vrow = rr ? r1_ : r0_;
    const uint4 v4 = *reinterpret_cast<const uint4*>(
        vpe + ((size_t)(b * 512 + h * 64 + ch2)) * 1024 + vrow * 32 + seg * 8);
    u16* dst = &vl[(rr * 64 + ch2) * 36 + seg * 8];
    uint2 lo, hi;
    lo.x = v4.x; lo.y = v4.y; hi.x = v4.z; hi.y = v4.w;
    *reinterpret_cast<uint2*>(dst)     = lo;
    *reinterpret_cast<uint2*>(dst + 4) = hi;
  }
  if (t < 64) gbl[t] = gbf[t];
  __syncthreads();

  // ---- phase B: fine, per wave (16 q-rows each) ----
  u16* fusw = &fus[(w * 16 + c) * 136];
  f32x4 st2[4];
#pragma unroll
  for (int mt = 0; mt < 4; ++mt) {
    f32x4 acc = (f32x4){0.f, 0.f, 0.f, 0.f};
#pragma unroll
    for (int s = 0; s < 2; ++s) {
      bf16x8 ak = *reinterpret_cast<const bf16x8*>(
          &tkb[((size_t)bh * 64 + mt * 16 + c) * 64 + s * 32 + quad * 8]);
      acc = __builtin_amdgcn_mfma_f32_16x16x32_bf16(ak, bq[s], acc, 0, 0, 0);
    }
    st2[mt] = acc;
  }
  float sume2 = 0.f;
#pragma unroll
  for (int mt = 0; mt < 4; ++mt) {
    float e0 = __expf(st2[mt][0]);
    float e1 = __expf(st2[mt][1]);
    float e2 = __expf(st2[mt][2]);
    float e3 = __expf(st2[mt][3]);
    sume2 += (e0 + e1) + (e2 + e3);
    ushort4 pw;
    pw.x = f2bs(e0); pw.y = f2bs(e1); pw.z = f2bs(e2); pw.w = f2bs(e3);
    *reinterpret_cast<ushort4*>(fusw + mt * 16 + quad * 4) = pw;
  }
  sume2 += __shfl_xor(sume2, 16, 64);
  sume2 += __shfl_xor(sume2, 32, 64);
  float inv2 = 1.0f / sume2;

  f32x4 po2[4];
#pragma unroll
  for (int dt = 0; dt < 4; ++dt) po2[dt] = (f32x4){0.f, 0.f, 0.f, 0.f};
#pragma unroll
  for (int s = 0; s < 2; ++s) {
    bf16x8 bp = *reinterpret_cast<const bf16x8*>(fusw + s * 32 + quad * 8);
#pragma unroll
    for (int dt = 0; dt < 4; ++dt) {
      bf16x8 av = *reinterpret_cast<const bf16x8*>(
          &tvTb[((size_t)bh * 64 + dt * 16 + c) * 64 + s * 32 + quad * 8]);
      po2[dt] = __builtin_amdgcn_mfma_f32_16x16x32_bf16(av, bp, po2[dt], 0, 0, 0);
    }
  }

  // fusion [coarse | refined]
  float invc = 1.0f / sume;
#pragma unroll
  for (int dt = 0; dt < 4; ++dt) {
    ushort4 cw, rw;
    cw.x = f2bs(po[dt][0] * invc); cw.y = f2bs(po[dt][1] * invc);
    cw.z = f2bs(po[dt][2] * invc); cw.w = f2bs(po[dt][3] * invc);
    rw.x = f2bs(po2[dt][0] * inv2); rw.y = f2bs(po2[dt][1] * inv2);
    rw.z = f2bs(po2[dt][2] * inv2); rw.w = f2bs(po2[dt][3] * inv2);
    *reinterpret_cast<ushort4*>(fusw + dt * 16 + quad * 4)      = cw;
    *reinterpret_cast<ushort4*>(fusw + 64 + dt * 16 + quad * 4) = rw;
  }

  // gate MFMA (K=128), A-frags from global gwb
  f32x4 ga[4];
#pragma unroll
  for (int ot = 0; ot < 4; ++ot) ga[ot] = (f32x4){0.f, 0.f, 0.f, 0.f};
#pragma unroll
  for (int s = 0; s < 4; ++s) {
    bf16x8 bf = *reinterpret_cast<const bf16x8*>(fusw + s * 32 + quad * 8);
#pragma unroll
    for (int ot = 0; ot < 4; ++ot) {
      bf16x8 ag = *reinterpret_cast<const bf16x8*>(
          gwb + (ot * 16 + c) * 128 + s * 32 + quad * 8);
      ga[ot] = __builtin_amdgcn_mfma_f32_16x16x32_bf16(ag, bf, ga[ot], 0, 0, 0);
    }
  }

  // combine + bilinear; overwrite fus rows 0..63 (same-lane read->write)
  const int x = w * 16 + c;              // x coordinate of this q-row
  int jx = x >> 1, x0, x1; float wx0, wx1;
  if ((x & 1) == 0) { x0 = (jx > 0) ? jx - 1 : 0; x1 = jx; wx0 = 0.25f; wx1 = 0.75f; }
  else              { x0 = jx; x1 = (jx < 31) ? jx + 1 : 31; wx0 = 0.75f; wx1 = 0.25f; }
#pragma unroll
  for (int dt = 0; dt < 4; ++dt) {
    ushort4 ow;
    u16 tmp[4];
#pragma unroll
    for (int r = 0; r < 4; ++r) {
      int row = dt * 16 + quad * 4 + r;
      float ref = po2[dt][r] * inv2;
      float coar = bs2f(fusw[row]);
      float g = 1.0f / (1.0f + __expf(-(ga[dt][r] + gbl[row])));
      float vv = wy0 * (wx0 * bs2f(vl[row * 36 + x0]) +
                        wx1 * bs2f(vl[row * 36 + x1])) +
                 wy1 * (wx0 * bs2f(vl[(64 + row) * 36 + x0]) +
                        wx1 * bs2f(vl[(64 + row) * 36 + x1]));
      tmp[r] = f2bs(g * ref + (1.0f - g) * coar + vv);
    }
    ow.x = tmp[0]; ow.y = tmp[1]; ow.z = tmp[2]; ow.w = tmp[3];
    *reinterpret_cast<ushort4*>(fusw + dt * 16 + quad * 4) = ow;
  }

  // store n-major rows (same-wave cross-lane reads, in-order DS)
  {
    int nl = lane >> 2, cs2 = (lane & 3) * 16;
    const u16* srcrow = &fus[(w * 16 + nl) * 136 + cs2];
    u16* dst = xsT + ((size_t)b * 4096 + n0 + w * 16 + nl) * 512 + h * 64 + cs2;
    *reinterpret_cast<uint4*>(dst)     = *reinterpret_cast<const uint4*>(srcrow);
    *reinterpret_cast<uint4*>(dst + 8) = *reinterpret_cast<const uint4*>(srcrow + 8);
  }
}

extern "C" void kernel_launch(void* const* d_in, const int* in_sizes, int n_in,
                              void* d_out, int out_size, void* d_ws, size_t ws_size,
                              hipStream_t stream) {
  const void* x    = d_in[0];
  const void* up   = d_in[1];
  const void* gum  = d_in[2];
  const void* q_w  = d_in[3];
  const void* q_b  = d_in[4];
  const void* kv_w = d_in[5];
  const void* kv_b = d_in[6];
  const void* p_w  = d_in[7];
  const void* p_b  = d_in[8];
  const void* pe_w = d_in[9];
  const void* pe_b = d_in[10];
  const void* g_w  = d_in[11];
  const void* g_b  = d_in[12];

  float* ws    = (float*)d_ws;
  int*   dtf   = (int*)ws;                   // 16 f
  float* qsum  = ws + 16;                    // 1024 f
  float* heat  = qsum + 1024;                // 2048 f
  int*   posb  = (int*)(heat + 2048);        // 1024 ints
  float* gbf   = (float*)(posb + 1024);      // 64
  u16*   gwb   = (u16*)(gbf + 64);           // 8192 u16
  u16*   tkb   = gwb + 8192;                 // 65536
  u16*   tvTb  = tkb + 65536;                // 65536
  u16*   qb    = tvTb + 65536;               // 4M
  u16*   kb    = qb + 4194304;               // 1M
  u16*   v2b   = kb + 1048576;               // 1M   (swizzled V)
  u16*   xT    = v2b + 1048576;              // 4M
  u16*   upT   = xT + 4194304;               // 1M
  u16*   xsT   = upT + 1048576;              // 4M
  u16*   vpe   = xsT + 4194304;              // 1M   (~26 MB total)

  dim3 blk(256);
  hipMemsetAsync(ws, 0, (16 + 1024 + 2048) * 4, stream);
  detect_dtype<<<dim3(64), blk, 0, stream>>>((const uint4*)x, dtf);
  prep_gate<<<dim3(1), blk, 0, stream>>>(g_w, g_b, gwb, gbf, dtf);
  transpose_bf16<<<dim3(64, 8, 2), blk, 0, stream>>>(x, xT, 4096, heat, dtf);
  transpose_bf16<<<dim3(16, 8, 2), blk, 0, stream>>>(up, upT, 1024, nullptr, dtf);
  gemm128<0><<<dim3(32, 8, 2), blk, 0, stream>>>(xT, q_w, q_b, qb, nullptr, qsum, 4096, dtf);
  gemm_kv<<<dim3(16, 16, 2), blk, 0, stream>>>(upT, kv_w, kv_b, kb, v2b, 1024, dtf);
  topk_kernel<<<dim3(16), blk, 0, stream>>>(qsum, kb, heat, gum, posb, dtf);
  gather_kv_mfma<<<dim3(16, 2), blk, 0, stream>>>(xT, kv_w, kv_b, posb, tkb, tvTb, dtf);
  dwconv_kernel<<<dim3(1024), blk, 0, stream>>>(v2b, pe_w, pe_b, vpe, dtf);
  attn_fused<<<dim3(64, 16), blk, 0, stream>>>(qb, kb, v2b, tkb, tvTb, gwb, gbf, vpe, xsT);
  gemm128<3><<<dim3(32, 8, 2), blk, 0, stream>>>(xsT, p_w, p_b, nullptr, d_out, nullptr, 4096, dtf);
}